// Round 10
// baseline (15172.548 us; speedup 1.0000x reference)
//
#include <hip/hip_runtime.h>
#include <float.h>

#define M_TOK 16384   // B*T
#define DIM   256
#define NCODE 1024
#define NQ    8
#define FEAT  756
#define DELTA 0.06f

using short8 = __attribute__((ext_vector_type(8))) short;  // 8 bf16
using f32x4  = __attribute__((ext_vector_type(4))) float;

__device__ __forceinline__ float fm(float a, float b) { return __fmul_rn(a, b); }
__device__ __forceinline__ float fa(float a, float b) { return __fadd_rn(a, b); }
__device__ __forceinline__ float fs(float a, float b) { return __fsub_rn(a, b); }

__device__ __forceinline__ unsigned fkey(float f) {
  unsigned b = __float_as_uint(f);
  return (b & 0x80000000u) ? ~b : (b | 0x80000000u);
}
__device__ __forceinline__ float funkey(unsigned k) {
  unsigned b = (k & 0x80000000u) ? (k & 0x7FFFFFFFu) : ~k;
  return __uint_as_float(b);
}
__device__ __forceinline__ unsigned short bf16rne(float x) {
  unsigned b = __float_as_uint(x);
  return (unsigned short)((b + 0x7FFFu + ((b >> 16) & 1u)) >> 16);
}

// ---- numpy pairwise_sum (SSE2-npyv) of squares ----
__device__ float pairwise128_sq(const float* a) {
  float V[8][4];
#pragma unroll
  for (int j = 0; j < 8; ++j)
#pragma unroll
    for (int l = 0; l < 4; ++l) { float x = a[4 * j + l]; V[j][l] = fm(x, x); }
#pragma unroll
  for (int t = 1; t < 4; ++t)
#pragma unroll
    for (int j = 0; j < 8; ++j)
#pragma unroll
      for (int l = 0; l < 4; ++l) {
        float x = a[32 * t + 4 * j + l];
        V[j][l] = fa(V[j][l], fm(x, x));
      }
  float W[4];
#pragma unroll
  for (int l = 0; l < 4; ++l) {
    float p01 = fa(V[0][l], V[1][l]), p23 = fa(V[2][l], V[3][l]);
    float p45 = fa(V[4][l], V[5][l]), p67 = fa(V[6][l], V[7][l]);
    W[l] = fa(fa(p01, p23), fa(p45, p67));
  }
  return fa(fa(W[0], W[2]), fa(W[1], W[3]));
}
__device__ float pairwise256_sq(const float* a) {
  return fa(pairwise128_sq(a), pairwise128_sq(a + 128));
}

// ---- numpy einsum contig_two f32 dot ----
__device__ float dot256_np(const float* __restrict__ r, const float* __restrict__ c) {
  float L0 = 0.f, L1 = 0.f, L2 = 0.f, L3 = 0.f;
#pragma unroll 8
  for (int t = 0; t < 64; ++t) {
    float4 rv = *reinterpret_cast<const float4*>(r + 4 * t);
    float4 cv = *reinterpret_cast<const float4*>(c + 4 * t);
    L0 = fa(L0, fm(rv.x, cv.x));
    L1 = fa(L1, fm(rv.y, cv.y));
    L2 = fa(L2, fm(rv.z, cv.z));
    L3 = fa(L3, fm(rv.w, cv.w));
  }
  return fa(fa(L0, L2), fa(L1, L3));
}

__device__ __forceinline__ void np_eval(const float* __restrict__ rrow,
                                        const float* __restrict__ crow,
                                        float t1, float t3, int code,
                                        unsigned long long* __restrict__ dst) {
  float e = dot256_np(rrow, crow);
  float dn = fa(fs(t1, fa(e, e)), t3);
  atomicMin(dst, ((unsigned long long)fkey(dn) << 32) | (unsigned)code);
}

// ---- z: np-exact sequential chain per (m,d); 8 tokens/block, 4d x 2t per thread ----
__global__ __launch_bounds__(256) void k_z(const float* __restrict__ in,
                                           const float* __restrict__ w_in,
                                           float* __restrict__ residual) {
  const int m0 = blockIdx.x * 8;
  __shared__ float xs[8][FEAT];
  for (int i = threadIdx.x; i < 8 * FEAT; i += 256)
    xs[i / FEAT][i % FEAT] = in[(size_t)m0 * FEAT + i];
  __syncthreads();
  const int dg = threadIdx.x & 63;        // d = dg*4 .. +3
  const int tg = threadIdx.x >> 6;        // tokens tg*2, tg*2+1
  float4 a0 = {0.f, 0.f, 0.f, 0.f}, a1 = {0.f, 0.f, 0.f, 0.f};
  for (int c = 0; c < 3; ++c)
    for (int f = 0; f < 252; ++f) {       // F = c*252+f ascending
      float4 w4 = *reinterpret_cast<const float4*>(&w_in[(size_t)(c * 252 + f) * DIM + dg * 4]);
      float x0 = xs[tg * 2 + 0][f * 3 + c];
      float x1 = xs[tg * 2 + 1][f * 3 + c];
      a0.x = fa(a0.x, fm(x0, w4.x)); a0.y = fa(a0.y, fm(x0, w4.y));
      a0.z = fa(a0.z, fm(x0, w4.z)); a0.w = fa(a0.w, fm(x0, w4.w));
      a1.x = fa(a1.x, fm(x1, w4.x)); a1.y = fa(a1.y, fm(x1, w4.y));
      a1.z = fa(a1.z, fm(x1, w4.z)); a1.w = fa(a1.w, fm(x1, w4.w));
    }
  *reinterpret_cast<float4*>(&residual[(size_t)(m0 + tg * 2 + 0) * DIM + dg * 4]) = a0;
  *reinterpret_cast<float4*>(&residual[(size_t)(m0 + tg * 2 + 1) * DIM + dg * 4]) = a1;
}

// ---- codebook row norms (np pairwise) ----
__global__ __launch_bounds__(256) void k_cbnorm(const float* __restrict__ cb,
                                                float* __restrict__ cbn) {
  int row = blockIdx.x * 256 + threadIdx.x;
  if (row >= NQ * NCODE) return;
  cbn[row] = pairwise256_sq(&cb[(size_t)row * DIM]);
}

// ---- codebook f32 -> bf16 bits ----
__global__ __launch_bounds__(256) void k_cb16(const float* __restrict__ cb,
                                              unsigned short* __restrict__ cb16) {
  size_t i = (size_t)blockIdx.x * 1024 + (size_t)threadIdx.x * 4;
  float4 v = *reinterpret_cast<const float4*>(&cb[i]);
  ushort4 o;
  o.x = bf16rne(v.x); o.y = bf16rne(v.y); o.z = bf16rne(v.z); o.w = bf16rne(v.w);
  *reinterpret_cast<ushort4*>(&cb16[i]) = o;
}

// ---- w_out transpose -> bf16 wT16[768][256] ----
__global__ __launch_bounds__(256) void k_wt(const float* __restrict__ w_out,
                                            unsigned short* __restrict__ wT16) {
  int n = blockIdx.x;            // 0..767
  int k = threadIdx.x;           // 0..255
  float v = (n < FEAT) ? w_out[(size_t)k * FEAT + n] : 0.f;
  wT16[(size_t)n * DIM + k] = bf16rne(v);
}

// ---- np token norms + per-q state reset ----
__global__ __launch_bounds__(256) void k_t1init(const float* __restrict__ residual,
                                                float* __restrict__ t1g,
                                                unsigned long long* __restrict__ best64,
                                                unsigned* __restrict__ gfast,
                                                unsigned* __restrict__ cnt) {
  int m = blockIdx.x * 256 + threadIdx.x;
  t1g[m] = pairwise256_sq(&residual[(size_t)m * DIM]);
  best64[m] = 0xFFFFFFFFFFFFFFFFull;
  gfast[m] = 0xFFFFFFFFu;
  if (m == 0) *cnt = 0;
}

// ---- MFMA bf16 screen: fast best + candidate list push (no serial tail) ----
__global__ __launch_bounds__(256) void k_screen(
    const unsigned short* __restrict__ cb16, const float* __restrict__ cb,
    const float* __restrict__ cbn, const float* __restrict__ residual,
    const float* __restrict__ t1g, unsigned long long* __restrict__ best64,
    unsigned* __restrict__ gfast, unsigned long long* __restrict__ list,
    unsigned* __restrict__ cnt, unsigned list_cap, int q) {
  __shared__ __align__(16) unsigned short Bs[64][264];
  __shared__ float cbn_s[256];
  const int m0 = blockIdx.x * 64;
  const int cbase = blockIdx.y * 256;
  const int tid = threadIdx.x, w = tid >> 6, lane = tid & 63;
  const int lrow = lane & 15, lk = lane >> 4;
  const unsigned short* cbq16 = cb16 + (size_t)q * NCODE * DIM;
  const float* cbqf = cb + (size_t)q * NCODE * DIM;

  cbn_s[tid] = cbn[q * NCODE + cbase + tid];

  const int mtokA = m0 + w * 16 + lrow;
  short8 afr[8];
  {
    const float* rrow = &residual[(size_t)mtokA * DIM];
#pragma unroll
    for (int s = 0; s < 8; ++s) {
      float4 x0 = *reinterpret_cast<const float4*>(&rrow[s * 32 + lk * 8]);
      float4 x1 = *reinterpret_cast<const float4*>(&rrow[s * 32 + lk * 8 + 4]);
      short8 t;
      t[0] = (short)bf16rne(x0.x); t[1] = (short)bf16rne(x0.y);
      t[2] = (short)bf16rne(x0.z); t[3] = (short)bf16rne(x0.w);
      t[4] = (short)bf16rne(x1.x); t[5] = (short)bf16rne(x1.y);
      t[6] = (short)bf16rne(x1.z); t[7] = (short)bf16rne(x1.w);
      afr[s] = t;
    }
  }

  float bv[4] = {FLT_MAX, FLT_MAX, FLT_MAX, FLT_MAX};
  int bi[4] = {0, 0, 0, 0};

  for (int ct = 0; ct < 4; ++ct) {
    __syncthreads();
    {  // stage B tile: 64 codes x 256 dims bf16
      int r = tid >> 2, seg = tid & 3;
      const uint4* src = reinterpret_cast<const uint4*>(
          &cbq16[(size_t)(cbase + ct * 64 + r) * DIM + seg * 64]);
      uint4* dst = reinterpret_cast<uint4*>(&Bs[r][seg * 64]);
#pragma unroll
      for (int u = 0; u < 8; ++u) dst[u] = src[u];
    }
    __syncthreads();

    f32x4 acc[4];
#pragma unroll
    for (int f = 0; f < 4; ++f) acc[f] = (f32x4){0.f, 0.f, 0.f, 0.f};
#pragma unroll
    for (int s = 0; s < 8; ++s) {
#pragma unroll
      for (int f = 0; f < 4; ++f) {
        short8 bfr = *reinterpret_cast<const short8*>(&Bs[f * 16 + lrow][s * 32 + lk * 8]);
        acc[f] = __builtin_amdgcn_mfma_f32_16x16x32_bf16(afr[s], bfr, acc[f], 0, 0, 0);
      }
    }

#pragma unroll
    for (int f = 0; f < 4; ++f) {
      const int codeL = ct * 64 + f * 16 + lrow;
      const int code = cbase + codeL;
      const float t3 = cbn_s[codeL];
#pragma unroll
      for (int r = 0; r < 4; ++r) {
        const float dfast = t3 - 2.0f * acc[f][r];
        float pd; int pi; bool push = false;
        if (dfast < bv[r]) {
          pd = bv[r]; pi = bi[r];
          bv[r] = dfast; bi[r] = code;
          push = (pd <= dfast + DELTA);
        } else if (dfast <= bv[r] + DELTA) {
          pd = dfast; pi = code; push = true;
        }
        if (push) {
          const int m = m0 + w * 16 + lk * 4 + r;
          unsigned idx = atomicAdd(cnt, 1u);
          if (idx < list_cap)
            list[idx] = ((unsigned long long)fkey(pd) << 32) |
                        ((unsigned)m << 10) | (unsigned)pi;
          else
            np_eval(&residual[(size_t)m * DIM], &cbqf[(size_t)pi * DIM],
                    t1g[m], cbn_s[pi - cbase], pi, &best64[m]);
        }
      }
    }
  }

  float fb[4] = {bv[0], bv[1], bv[2], bv[3]};
#pragma unroll
  for (int off = 8; off >= 1; off >>= 1)
#pragma unroll
    for (int r = 0; r < 4; ++r)
      fb[r] = fminf(fb[r], __shfl_xor(fb[r], off, 64));

#pragma unroll
  for (int r = 0; r < 4; ++r) {
    const int m = m0 + w * 16 + lk * 4 + r;
    if (lrow == 0) atomicMin(&gfast[m], fkey(fb[r]));
    if (bv[r] <= fb[r] + DELTA) {
      unsigned idx = atomicAdd(cnt, 1u);
      if (idx < list_cap)
        list[idx] = ((unsigned long long)fkey(bv[r]) << 32) |
                    ((unsigned)m << 10) | (unsigned)bi[r];
      else
        np_eval(&residual[(size_t)m * DIM], &cbqf[(size_t)bi[r] * DIM],
                t1g[m], cbn_s[bi[r] - cbase], bi[r], &best64[m]);
    }
  }
}

// ---- compacted repair: np-exact eval of candidates near the global fast best ----
__global__ __launch_bounds__(256) void k_repair(
    const unsigned long long* __restrict__ list, const unsigned* __restrict__ cnt,
    unsigned list_cap, const unsigned* __restrict__ gfast,
    const float* __restrict__ cb, const float* __restrict__ cbn,
    const float* __restrict__ residual, const float* __restrict__ t1g,
    unsigned long long* __restrict__ best64, int q) {
  unsigned n = *cnt; if (n > list_cap) n = list_cap;
  const float* cbqf = cb + (size_t)q * NCODE * DIM;
  for (unsigned i = blockIdx.x * 256 + threadIdx.x; i < n; i += gridDim.x * 256) {
    unsigned long long e = list[i];
    int code = (int)(e & 1023u);
    int m = (int)((e >> 10) & 16383u);
    float df = funkey((unsigned)(e >> 32));
    if (df <= funkey(gfast[m]) + DELTA)
      np_eval(&residual[(size_t)m * DIM], &cbqf[(size_t)code * DIM],
              t1g[m], cbn[q * NCODE + code], code, &best64[m]);
  }
}

// ---- update: residual step (np fs), allq, qsum, idx ----
__global__ __launch_bounds__(256) void k_upd(const float* __restrict__ cb,
                                             float* __restrict__ residual,
                                             float* __restrict__ qsum,
                                             float* __restrict__ allq,
                                             float* __restrict__ idxout,
                                             const unsigned long long* __restrict__ best64,
                                             int q) {
  const int m0 = blockIdx.x * 16;
  const int lane = threadIdx.x & 63, w = threadIdx.x >> 6;
  const float* cbq = cb + (size_t)q * NCODE * DIM;
  for (int t = 0; t < 4; ++t) {
    const size_t m = (size_t)m0 + w * 4 + t;
    const int ci = (int)(best64[m] & 0xFFFFFFFFull);
    const float4 cv = *reinterpret_cast<const float4*>(&cbq[(size_t)ci * DIM + lane * 4]);
    const size_t base = m * DIM + lane * 4;
    float4 r = *reinterpret_cast<const float4*>(&residual[base]);
    r.x = fs(r.x, cv.x); r.y = fs(r.y, cv.y); r.z = fs(r.z, cv.z); r.w = fs(r.w, cv.w);
    *reinterpret_cast<float4*>(&residual[base]) = r;
    *reinterpret_cast<float4*>(&allq[((size_t)q * M_TOK + m) * DIM + lane * 4]) = cv;
    if (q == 0) {
      *reinterpret_cast<float4*>(&qsum[base]) = cv;
    } else {
      float4 s4 = *reinterpret_cast<const float4*>(&qsum[base]);
      s4.x += cv.x; s4.y += cv.y; s4.z += cv.z; s4.w += cv.w;
      *reinterpret_cast<float4*>(&qsum[base]) = s4;
    }
    if (lane == 0) idxout[m * NQ + q] = (float)ci;
  }
}

// ---- quantized = relu( qsum @ w_out ), MFMA bf16 ----
__global__ __launch_bounds__(256) void k_gemm_out(const float* __restrict__ qsum,
                                                  const unsigned short* __restrict__ wT16,
                                                  float* __restrict__ C) {
  __shared__ __align__(16) unsigned short Bs[64][264];
  const int m0 = blockIdx.x * 64;
  const int n0 = blockIdx.y * 64;
  const int tid = threadIdx.x, w = tid >> 6, lane = tid & 63;
  const int lrow = lane & 15, lk = lane >> 4;

  {  // stage B: 64 out-cols x 256 k bf16
    int r = tid >> 2, seg = tid & 3;
    const uint4* src = reinterpret_cast<const uint4*>(&wT16[(size_t)(n0 + r) * DIM + seg * 64]);
    uint4* dst = reinterpret_cast<uint4*>(&Bs[r][seg * 64]);
#pragma unroll
    for (int u = 0; u < 8; ++u) dst[u] = src[u];
  }

  const int mtokA = m0 + w * 16 + lrow;
  short8 afr[8];
  {
    const float* arow = &qsum[(size_t)mtokA * DIM];
#pragma unroll
    for (int s = 0; s < 8; ++s) {
      float4 x0 = *reinterpret_cast<const float4*>(&arow[s * 32 + lk * 8]);
      float4 x1 = *reinterpret_cast<const float4*>(&arow[s * 32 + lk * 8 + 4]);
      short8 t;
      t[0] = (short)bf16rne(x0.x); t[1] = (short)bf16rne(x0.y);
      t[2] = (short)bf16rne(x0.z); t[3] = (short)bf16rne(x0.w);
      t[4] = (short)bf16rne(x1.x); t[5] = (short)bf16rne(x1.y);
      t[6] = (short)bf16rne(x1.z); t[7] = (short)bf16rne(x1.w);
      afr[s] = t;
    }
  }
  __syncthreads();

  f32x4 acc[4];
#pragma unroll
  for (int f = 0; f < 4; ++f) acc[f] = (f32x4){0.f, 0.f, 0.f, 0.f};
#pragma unroll
  for (int s = 0; s < 8; ++s) {
#pragma unroll
    for (int f = 0; f < 4; ++f) {
      short8 bfr = *reinterpret_cast<const short8*>(&Bs[f * 16 + lrow][s * 32 + lk * 8]);
      acc[f] = __builtin_amdgcn_mfma_f32_16x16x32_bf16(afr[s], bfr, acc[f], 0, 0, 0);
    }
  }

#pragma unroll
  for (int f = 0; f < 4; ++f) {
    const int col = n0 + f * 16 + lrow;
    if (col < FEAT) {
#pragma unroll
      for (int r = 0; r < 4; ++r)
        C[(size_t)(m0 + w * 16 + lk * 4 + r) * FEAT + col] = fmaxf(acc[f][r], 0.f);
    }
  }
}

extern "C" void kernel_launch(void* const* d_in, const int* in_sizes, int n_in,
                              void* d_out, int out_size, void* d_ws, size_t ws_size,
                              hipStream_t stream) {
  int i_inputs = 0, i_cb = 1, iA = 2, iB = 3;
  {
    int a = -1, b = -1, ii = -1, ic = -1;
    for (int i = 0; i < n_in; ++i) {
      if (in_sizes[i] == M_TOK * FEAT) ii = i;
      else if (in_sizes[i] == NQ * NCODE * DIM) ic = i;
      else if (in_sizes[i] == FEAT * DIM) { if (a < 0) a = i; else b = i; }
    }
    if (ii >= 0 && ic >= 0 && a >= 0 && b >= 0) { i_inputs = ii; i_cb = ic; iA = a; iB = b; }
  }
  const float* inputs = (const float*)d_in[i_inputs];
  const float* cb     = (const float*)d_in[i_cb];
  const float* w_in   = (const float*)d_in[iA];
  const float* w_out  = (const float*)d_in[iB];

  float* out       = (float*)d_out;
  float* quantized = out;                                 // 16384*756
  float* allq      = out + (size_t)M_TOK * FEAT;          // 8*16384*256
  float* idxout    = allq + (size_t)NQ * M_TOK * DIM;     // 16384*8

  // residual (16.8MB) lives in the quantized region (dead before k_gemm_out).
  float* residual = quantized;

  // Everything k_gemm_out reads lives in d_ws (no read/write overlap with output).
  char* ws = (char*)d_ws;
  float*              qsum   = (float*)(ws);                          // 16,777,216 B
  unsigned short*     cb16   = (unsigned short*)(ws + 16777216);      //  4,194,304 B
  unsigned short*     wT16   = (unsigned short*)(ws + 20971520);      //    393,216 B
  float*              cbn    = (float*)(ws + 21364736);               //     32,768 B
  float*              t1g    = (float*)(ws + 21397504);               //     65,536 B
  unsigned*           gfast  = (unsigned*)(ws + 21463040);            //     65,536 B
  unsigned*           cnt    = (unsigned*)(ws + 21528576);            //         64 B
  unsigned long long* best64 = (unsigned long long*)(ws + 21528640);  //    131,072 B
  unsigned long long* list   = (unsigned long long*)(ws + 21659712);
  size_t list_bytes = (ws_size > 21659712u + 4096u) ? ws_size - 21659712u - 4096u : 0u;
  unsigned list_cap = (unsigned)((list_bytes / 8u < 1500000u) ? list_bytes / 8u : 1500000u);

  k_z<<<M_TOK / 8, 256, 0, stream>>>(inputs, w_in, residual);
  k_cbnorm<<<NQ * NCODE / 256, 256, 0, stream>>>(cb, cbn);
  k_cb16<<<NQ * NCODE * DIM / 1024, 256, 0, stream>>>(cb, cb16);
  k_wt<<<768, 256, 0, stream>>>(w_out, wT16);
  for (int q = 0; q < NQ; ++q) {
    k_t1init<<<M_TOK / 256, 256, 0, stream>>>(residual, t1g, best64, gfast, cnt);
    k_screen<<<dim3(M_TOK / 64, NCODE / 256), 256, 0, stream>>>(
        cb16, cb, cbn, residual, t1g, best64, gfast, list, cnt, list_cap, q);
    k_repair<<<256, 256, 0, stream>>>(list, cnt, list_cap, gfast, cb, cbn,
                                      residual, t1g, best64, q);
    k_upd<<<M_TOK / 16, 256, 0, stream>>>(cb, residual, qsum, allq, idxout, best64, q);
  }
  k_gemm_out<<<dim3(M_TOK / 64, 768 / 64), 256, 0, stream>>>(qsum, wT16, quantized);
}

// Round 11
// 1068.800 us; speedup vs baseline: 14.1959x; 14.1959x over previous
//
#include <hip/hip_runtime.h>
#include <float.h>

#define M_TOK 16384   // B*T
#define DIM   256
#define NCODE 1024
#define NQ    8
#define FEAT  756
#define DSCALE 0.00375f   // DELTA = DSCALE*sqrt(t1): == 0.06 at q=0, ~23 sigma of bf16 noise
#define LCAP  4096
#define L2CAP 512

using short8 = __attribute__((ext_vector_type(8))) short;  // 8 bf16
using f32x4  = __attribute__((ext_vector_type(4))) float;

__device__ __forceinline__ float fm(float a, float b) { return __fmul_rn(a, b); }
__device__ __forceinline__ float fa(float a, float b) { return __fadd_rn(a, b); }
__device__ __forceinline__ float fs(float a, float b) { return __fsub_rn(a, b); }

__device__ __forceinline__ unsigned fkey(float f) {
  unsigned b = __float_as_uint(f);
  return (b & 0x80000000u) ? ~b : (b | 0x80000000u);
}
__device__ __forceinline__ float funkey(unsigned k) {
  unsigned b = (k & 0x80000000u) ? (k & 0x7FFFFFFFu) : ~k;
  return __uint_as_float(b);
}
__device__ __forceinline__ unsigned short bf16rne(float x) {
  unsigned b = __float_as_uint(x);
  return (unsigned short)((b + 0x7FFFu + ((b >> 16) & 1u)) >> 16);
}

// ---- numpy pairwise_sum (SSE2-npyv) of squares ----
__device__ float pairwise128_sq(const float* a) {
  float V[8][4];
#pragma unroll
  for (int j = 0; j < 8; ++j)
#pragma unroll
    for (int l = 0; l < 4; ++l) { float x = a[4 * j + l]; V[j][l] = fm(x, x); }
#pragma unroll
  for (int t = 1; t < 4; ++t)
#pragma unroll
    for (int j = 0; j < 8; ++j)
#pragma unroll
      for (int l = 0; l < 4; ++l) {
        float x = a[32 * t + 4 * j + l];
        V[j][l] = fa(V[j][l], fm(x, x));
      }
  float W[4];
#pragma unroll
  for (int l = 0; l < 4; ++l) {
    float p01 = fa(V[0][l], V[1][l]), p23 = fa(V[2][l], V[3][l]);
    float p45 = fa(V[4][l], V[5][l]), p67 = fa(V[6][l], V[7][l]);
    W[l] = fa(fa(p01, p23), fa(p45, p67));
  }
  return fa(fa(W[0], W[2]), fa(W[1], W[3]));
}
__device__ float pairwise256_sq(const float* a) {
  return fa(pairwise128_sq(a), pairwise128_sq(a + 128));
}

// ---- numpy einsum contig_two f32 dot (serial form, for rare overflow fallback) ----
__device__ float dot256_np(const float* __restrict__ r, const float* __restrict__ c) {
  float L0 = 0.f, L1 = 0.f, L2 = 0.f, L3 = 0.f;
#pragma unroll 8
  for (int t = 0; t < 64; ++t) {
    float4 rv = *reinterpret_cast<const float4*>(r + 4 * t);
    float4 cv = *reinterpret_cast<const float4*>(c + 4 * t);
    L0 = fa(L0, fm(rv.x, cv.x));
    L1 = fa(L1, fm(rv.y, cv.y));
    L2 = fa(L2, fm(rv.z, cv.z));
    L3 = fa(L3, fm(rv.w, cv.w));
  }
  return fa(fa(L0, L2), fa(L1, L3));
}

__device__ __forceinline__ void np_eval(const float* __restrict__ rrow,
                                        const float* __restrict__ crow,
                                        float t1, float t3, int code,
                                        unsigned long long* __restrict__ dst) {
  float e = dot256_np(rrow, crow);
  float dn = fa(fs(t1, fa(e, e)), t3);
  atomicMin(dst, ((unsigned long long)fkey(dn) << 32) | (unsigned)code);
}

// ---- z: np-exact sequential chain per (m,d); 8 tokens/block, 4d x 2t per thread ----
__global__ __launch_bounds__(256) void k_z(const float* __restrict__ in,
                                           const float* __restrict__ w_in,
                                           float* __restrict__ residual) {
  const int m0 = blockIdx.x * 8;
  __shared__ float xs[8][FEAT];
  for (int i = threadIdx.x; i < 8 * FEAT; i += 256)
    xs[i / FEAT][i % FEAT] = in[(size_t)m0 * FEAT + i];
  __syncthreads();
  const int dg = threadIdx.x & 63;
  const int tg = threadIdx.x >> 6;
  float4 a0 = {0.f, 0.f, 0.f, 0.f}, a1 = {0.f, 0.f, 0.f, 0.f};
  for (int c = 0; c < 3; ++c)
    for (int f = 0; f < 252; ++f) {
      float4 w4 = *reinterpret_cast<const float4*>(&w_in[(size_t)(c * 252 + f) * DIM + dg * 4]);
      float x0 = xs[tg * 2 + 0][f * 3 + c];
      float x1 = xs[tg * 2 + 1][f * 3 + c];
      a0.x = fa(a0.x, fm(x0, w4.x)); a0.y = fa(a0.y, fm(x0, w4.y));
      a0.z = fa(a0.z, fm(x0, w4.z)); a0.w = fa(a0.w, fm(x0, w4.w));
      a1.x = fa(a1.x, fm(x1, w4.x)); a1.y = fa(a1.y, fm(x1, w4.y));
      a1.z = fa(a1.z, fm(x1, w4.z)); a1.w = fa(a1.w, fm(x1, w4.w));
    }
  *reinterpret_cast<float4*>(&residual[(size_t)(m0 + tg * 2 + 0) * DIM + dg * 4]) = a0;
  *reinterpret_cast<float4*>(&residual[(size_t)(m0 + tg * 2 + 1) * DIM + dg * 4]) = a1;
}

// ---- codebook row norms (np pairwise) ----
__global__ __launch_bounds__(256) void k_cbnorm(const float* __restrict__ cb,
                                                float* __restrict__ cbn) {
  int row = blockIdx.x * 256 + threadIdx.x;
  if (row >= NQ * NCODE) return;
  cbn[row] = pairwise256_sq(&cb[(size_t)row * DIM]);
}

// ---- codebook f32 -> bf16 bits ----
__global__ __launch_bounds__(256) void k_cb16(const float* __restrict__ cb,
                                              unsigned short* __restrict__ cb16) {
  size_t i = (size_t)blockIdx.x * 1024 + (size_t)threadIdx.x * 4;
  float4 v = *reinterpret_cast<const float4*>(&cb[i]);
  ushort4 o;
  o.x = bf16rne(v.x); o.y = bf16rne(v.y); o.z = bf16rne(v.z); o.w = bf16rne(v.w);
  *reinterpret_cast<ushort4*>(&cb16[i]) = o;
}

// ---- w_out transpose -> bf16 wT16[768][256] ----
__global__ __launch_bounds__(256) void k_wt(const float* __restrict__ w_out,
                                            unsigned short* __restrict__ wT16) {
  int n = blockIdx.x, k = threadIdx.x;
  float v = (n < FEAT) ? w_out[(size_t)k * FEAT + n] : 0.f;
  wT16[(size_t)n * DIM + k] = bf16rne(v);
}

// ---- np token norms + best64 reset ----
__global__ __launch_bounds__(256) void k_t1(const float* __restrict__ residual,
                                            float* __restrict__ t1g,
                                            unsigned long long* __restrict__ best64) {
  int m = blockIdx.x * 256 + threadIdx.x;
  t1g[m] = pairwise256_sq(&residual[(size_t)m * DIM]);
  best64[m] = 0xFFFFFFFFFFFFFFFFull;
}

// ---- fused: MFMA screen (all 1024 codes) + LDS-compacted np repair + update ----
__global__ __launch_bounds__(256) void k_screen(
    const unsigned short* __restrict__ cb16, const float* __restrict__ cb,
    const float* __restrict__ cbn, float* __restrict__ residual,
    const float* __restrict__ t1g, unsigned long long* __restrict__ best64,
    float* __restrict__ qsum, float* __restrict__ allq,
    float* __restrict__ idxout, int q) {
  __shared__ __align__(16) unsigned short Bs[64][264];
  __shared__ float cbn_s[NCODE];
  __shared__ unsigned long long list[LCAP];
  __shared__ unsigned list2[L2CAP];
  __shared__ float fbs[64], t1_s[64], dlt_s[64];
  __shared__ unsigned lcnt, l2cnt;
  const int m0 = blockIdx.x * 64;
  const int tid = threadIdx.x, w = tid >> 6, lane = tid & 63;
  const int lrow = lane & 15, lk = lane >> 4;
  const unsigned short* cbq16 = cb16 + (size_t)q * NCODE * DIM;
  const float* cbqf = cb + (size_t)q * NCODE * DIM;

  for (int i = tid; i < NCODE; i += 256) cbn_s[i] = cbn[q * NCODE + i];
  if (tid < 64) {
    float t1 = t1g[m0 + tid];
    t1_s[tid] = t1;
    dlt_s[tid] = fmaxf(DSCALE * sqrtf(fmaxf(t1, 0.f)), 1e-5f);
  }
  if (tid == 0) { lcnt = 0; l2cnt = 0; }

  // A fragments: token = m0 + w*16 + lrow, k = s*32 + lk*8 + j
  short8 afr[8];
  {
    const float* rrow = &residual[(size_t)(m0 + w * 16 + lrow) * DIM];
#pragma unroll
    for (int s = 0; s < 8; ++s) {
      float4 x0 = *reinterpret_cast<const float4*>(&rrow[s * 32 + lk * 8]);
      float4 x1 = *reinterpret_cast<const float4*>(&rrow[s * 32 + lk * 8 + 4]);
      short8 t;
      t[0] = (short)bf16rne(x0.x); t[1] = (short)bf16rne(x0.y);
      t[2] = (short)bf16rne(x0.z); t[3] = (short)bf16rne(x0.w);
      t[4] = (short)bf16rne(x1.x); t[5] = (short)bf16rne(x1.y);
      t[6] = (short)bf16rne(x1.z); t[7] = (short)bf16rne(x1.w);
      afr[s] = t;
    }
  }
  __syncthreads();

  const int tokbase = w * 16 + lk * 4;          // + r = this thread's token rows
  float dl[4];
#pragma unroll
  for (int r = 0; r < 4; ++r) dl[r] = dlt_s[tokbase + r];
  float runmin[4] = {FLT_MAX, FLT_MAX, FLT_MAX, FLT_MAX};
  int runcode[4] = {0, 0, 0, 0};

#define PUSH(PD, PC, R)                                                          \
  {                                                                              \
    unsigned idx_ = atomicAdd(&lcnt, 1u);                                        \
    unsigned lo_ = ((unsigned)(tokbase + (R)) << 10) | (unsigned)(PC);           \
    if (idx_ < LCAP)                                                             \
      list[idx_] = ((unsigned long long)fkey(PD) << 32) | lo_;                   \
    else                                                                         \
      np_eval(&residual[(size_t)(m0 + tokbase + (R)) * DIM],                     \
              &cbqf[(size_t)(PC) * DIM], t1_s[tokbase + (R)], cbn_s[(PC)],       \
              (PC), &best64[m0 + tokbase + (R)]);                                \
  }

  for (int ct = 0; ct < 16; ++ct) {
    __syncthreads();
    {  // stage 64 codes x 256 dims bf16
      int r = tid >> 2, seg = tid & 3;
      const uint4* src = reinterpret_cast<const uint4*>(
          &cbq16[(size_t)(ct * 64 + r) * DIM + seg * 64]);
      uint4* dst = reinterpret_cast<uint4*>(&Bs[r][seg * 64]);
#pragma unroll
      for (int u = 0; u < 8; ++u) dst[u] = src[u];
    }
    __syncthreads();

    f32x4 acc[4];
#pragma unroll
    for (int f = 0; f < 4; ++f) acc[f] = (f32x4){0.f, 0.f, 0.f, 0.f};
#pragma unroll
    for (int s = 0; s < 8; ++s) {
#pragma unroll
      for (int f = 0; f < 4; ++f) {
        short8 bfr = *reinterpret_cast<const short8*>(&Bs[f * 16 + lrow][s * 32 + lk * 8]);
        acc[f] = __builtin_amdgcn_mfma_f32_16x16x32_bf16(afr[s], bfr, acc[f], 0, 0, 0);
      }
    }

#pragma unroll
    for (int f = 0; f < 4; ++f) {
      const int code = ct * 64 + f * 16 + lrow;
      const float t3 = cbn_s[code];
#pragma unroll
      for (int r = 0; r < 4; ++r) {
        const float d = t3 - 2.0f * acc[f][r];
        if (d < runmin[r]) {
          if (runmin[r] <= d + dl[r]) PUSH(runmin[r], runcode[r], r);  // displaced, still near
          runmin[r] = d; runcode[r] = code;
        } else if (d <= runmin[r] + dl[r]) {
          PUSH(d, code, r);
        }
      }
    }
  }
  // final running best is always a candidate
#pragma unroll
  for (int r = 0; r < 4; ++r) PUSH(runmin[r], runcode[r], r);

  // final per-token fast best over all 1024 codes (16 lrow lanes)
  float fb[4] = {runmin[0], runmin[1], runmin[2], runmin[3]};
#pragma unroll
  for (int off = 8; off >= 1; off >>= 1)
#pragma unroll
    for (int r = 0; r < 4; ++r)
      fb[r] = fminf(fb[r], __shfl_xor(fb[r], off, 64));
  if (lrow == 0)
#pragma unroll
    for (int r = 0; r < 4; ++r) fbs[tokbase + r] = fb[r];
  __syncthreads();

  // filter list -> compact survivors (within DELTA of final fast best)
  {
    unsigned n = lcnt; if (n > LCAP) n = LCAP;
    for (unsigned i = tid; i < n; i += 256) {
      unsigned long long e = list[i];
      unsigned lo = (unsigned)e;
      unsigned tok = (lo >> 10) & 63u;
      float df = funkey((unsigned)(e >> 32));
      if (df <= fbs[tok] + dlt_s[tok]) {
        unsigned j = atomicAdd(&l2cnt, 1u);
        if (j < L2CAP) list2[j] = lo & 0xFFFFu;
        else np_eval(&residual[(size_t)(m0 + tok) * DIM],
                     &cbqf[(size_t)(lo & 1023u) * DIM], t1_s[tok],
                     cbn_s[lo & 1023u], (int)(lo & 1023u), &best64[m0 + tok]);
      }
    }
  }
  __syncthreads();

  // cooperative np-exact repair: 16 candidates/wave, 4 lanes each (numpy's 4 accumulators)
  {
    unsigned n2 = l2cnt; if (n2 > L2CAP) n2 = L2CAP;
    const int j4 = lane & 3, g = lane >> 2;
    for (unsigned i0 = (unsigned)w * 16u; i0 < n2; i0 += 64u) {
      unsigned ci = i0 + (unsigned)g;
      bool act = ci < n2;
      unsigned ent = act ? list2[ci] : 0u;
      unsigned tok = (ent >> 10) & 63u, code = ent & 1023u;
      const float* rr = &residual[(size_t)(m0 + tok) * DIM];
      const float* cc = &cbqf[(size_t)code * DIM];
      float L = 0.f;
#pragma unroll 8
      for (int t = 0; t < 64; ++t)
        L = fa(L, fm(rr[4 * t + j4], cc[4 * t + j4]));
      float tmp = fa(L, __shfl_xor(L, 2, 64));       // lane0: L0+L2, lane1: L1+L3
      float e4 = fa(tmp, __shfl_xor(tmp, 1, 64));    // lane0: (L0+L2)+(L1+L3)
      if (act && j4 == 0) {
        float dn = fa(fs(t1_s[tok], fa(e4, e4)), cbn_s[code]);
        atomicMin(&best64[m0 + tok],
                  ((unsigned long long)fkey(dn) << 32) | code);
      }
    }
  }
  __syncthreads();

  // fused update: residual step (np fs), allq, qsum, idx — 16 tokens per wave
  for (int t = 0; t < 16; ++t) {
    const int tok = w * 16 + t;
    const size_t m = (size_t)m0 + tok;
    const int ci = (int)(best64[m] & 0xFFFFFFFFull);
    const float4 cv = *reinterpret_cast<const float4*>(&cbqf[(size_t)ci * DIM + lane * 4]);
    const size_t base = m * DIM + lane * 4;
    float4 r = *reinterpret_cast<const float4*>(&residual[base]);
    r.x = fs(r.x, cv.x); r.y = fs(r.y, cv.y); r.z = fs(r.z, cv.z); r.w = fs(r.w, cv.w);
    *reinterpret_cast<float4*>(&residual[base]) = r;
    *reinterpret_cast<float4*>(&allq[((size_t)q * M_TOK + m) * DIM + lane * 4]) = cv;
    if (q == 0) {
      *reinterpret_cast<float4*>(&qsum[base]) = cv;
    } else {
      float4 s4 = *reinterpret_cast<const float4*>(&qsum[base]);
      s4.x += cv.x; s4.y += cv.y; s4.z += cv.z; s4.w += cv.w;
      *reinterpret_cast<float4*>(&qsum[base]) = s4;
    }
    if (lane == 0) idxout[m * NQ + q] = (float)ci;
  }
#undef PUSH
}

// ---- quantized = relu( qsum @ w_out ), MFMA bf16 ----
__global__ __launch_bounds__(256) void k_gemm_out(const float* __restrict__ qsum,
                                                  const unsigned short* __restrict__ wT16,
                                                  float* __restrict__ C) {
  __shared__ __align__(16) unsigned short Bs[64][264];
  const int m0 = blockIdx.x * 64;
  const int n0 = blockIdx.y * 64;
  const int tid = threadIdx.x, w = tid >> 6, lane = tid & 63;
  const int lrow = lane & 15, lk = lane >> 4;

  {
    int r = tid >> 2, seg = tid & 3;
    const uint4* src = reinterpret_cast<const uint4*>(&wT16[(size_t)(n0 + r) * DIM + seg * 64]);
    uint4* dst = reinterpret_cast<uint4*>(&Bs[r][seg * 64]);
#pragma unroll
    for (int u = 0; u < 8; ++u) dst[u] = src[u];
  }

  short8 afr[8];
  {
    const float* arow = &qsum[(size_t)(m0 + w * 16 + lrow) * DIM];
#pragma unroll
    for (int s = 0; s < 8; ++s) {
      float4 x0 = *reinterpret_cast<const float4*>(&arow[s * 32 + lk * 8]);
      float4 x1 = *reinterpret_cast<const float4*>(&arow[s * 32 + lk * 8 + 4]);
      short8 t;
      t[0] = (short)bf16rne(x0.x); t[1] = (short)bf16rne(x0.y);
      t[2] = (short)bf16rne(x0.z); t[3] = (short)bf16rne(x0.w);
      t[4] = (short)bf16rne(x1.x); t[5] = (short)bf16rne(x1.y);
      t[6] = (short)bf16rne(x1.z); t[7] = (short)bf16rne(x1.w);
      afr[s] = t;
    }
  }
  __syncthreads();

  f32x4 acc[4];
#pragma unroll
  for (int f = 0; f < 4; ++f) acc[f] = (f32x4){0.f, 0.f, 0.f, 0.f};
#pragma unroll
  for (int s = 0; s < 8; ++s) {
#pragma unroll
    for (int f = 0; f < 4; ++f) {
      short8 bfr = *reinterpret_cast<const short8*>(&Bs[f * 16 + lrow][s * 32 + lk * 8]);
      acc[f] = __builtin_amdgcn_mfma_f32_16x16x32_bf16(afr[s], bfr, acc[f], 0, 0, 0);
    }
  }

#pragma unroll
  for (int f = 0; f < 4; ++f) {
    const int col = n0 + f * 16 + lrow;
    if (col < FEAT) {
#pragma unroll
      for (int r = 0; r < 4; ++r)
        C[(size_t)(m0 + w * 16 + lk * 4 + r) * FEAT + col] = fmaxf(acc[f][r], 0.f);
    }
  }
}

extern "C" void kernel_launch(void* const* d_in, const int* in_sizes, int n_in,
                              void* d_out, int out_size, void* d_ws, size_t ws_size,
                              hipStream_t stream) {
  int i_inputs = 0, i_cb = 1, iA = 2, iB = 3;
  {
    int a = -1, b = -1, ii = -1, ic = -1;
    for (int i = 0; i < n_in; ++i) {
      if (in_sizes[i] == M_TOK * FEAT) ii = i;
      else if (in_sizes[i] == NQ * NCODE * DIM) ic = i;
      else if (in_sizes[i] == FEAT * DIM) { if (a < 0) a = i; else b = i; }
    }
    if (ii >= 0 && ic >= 0 && a >= 0 && b >= 0) { i_inputs = ii; i_cb = ic; iA = a; iB = b; }
  }
  const float* inputs = (const float*)d_in[i_inputs];
  const float* cb     = (const float*)d_in[i_cb];
  const float* w_in   = (const float*)d_in[iA];
  const float* w_out  = (const float*)d_in[iB];

  float* out       = (float*)d_out;
  float* quantized = out;                                 // 16384*756
  float* allq      = out + (size_t)M_TOK * FEAT;          // 8*16384*256
  float* idxout    = allq + (size_t)NQ * M_TOK * DIM;     // 16384*8

  // residual (16.8MB) lives in the quantized region (dead before k_gemm_out).
  float* residual = quantized;

  // Everything k_gemm_out reads lives in d_ws.
  char* ws = (char*)d_ws;
  float*              qsum   = (float*)(ws);                          // 16,777,216 B
  unsigned short*     cb16   = (unsigned short*)(ws + 16777216);      //  4,194,304 B
  unsigned short*     wT16   = (unsigned short*)(ws + 20971520);      //    393,216 B
  float*              cbn    = (float*)(ws + 21364736);               //     32,768 B
  float*              t1g    = (float*)(ws + 21397504);               //     65,536 B
  unsigned long long* best64 = (unsigned long long*)(ws + 21463040);  //    131,072 B
  // total ~21.6 MB

  k_z<<<M_TOK / 8, 256, 0, stream>>>(inputs, w_in, residual);
  k_cbnorm<<<NQ * NCODE / 256, 256, 0, stream>>>(cb, cbn);
  k_cb16<<<NQ * NCODE * DIM / 1024, 256, 0, stream>>>(cb, cb16);
  k_wt<<<768, 256, 0, stream>>>(w_out, wT16);
  k_t1<<<M_TOK / 256, 256, 0, stream>>>(residual, t1g, best64);
  for (int q = 0; q < NQ; ++q) {
    k_screen<<<M_TOK / 64, 256, 0, stream>>>(cb16, cb, cbn, residual, t1g, best64,
                                             qsum, allq, idxout, q);
    if (q < NQ - 1)
      k_t1<<<M_TOK / 256, 256, 0, stream>>>(residual, t1g, best64);
  }
  k_gemm_out<<<dim3(M_TOK / 64, 768 / 64), 256, 0, stream>>>(qsum, wT16, quantized);
}

// Round 12
// 1009.395 us; speedup vs baseline: 15.0313x; 1.0589x over previous
//
#include <hip/hip_runtime.h>
#include <float.h>

#define M_TOK 16384   // B*T
#define DIM   256
#define NCODE 1024
#define NQ    8
#define FEAT  756
#define DSCALE 0.00375f   // DELTA = DSCALE*sqrt(t1): == 0.06 at q=0, ~23 sigma of bf16 noise
#define LCAP  4096
#define L2CAP 512

using short8 = __attribute__((ext_vector_type(8))) short;  // 8 bf16
using f32x4  = __attribute__((ext_vector_type(4))) float;

__device__ __forceinline__ float fm(float a, float b) { return __fmul_rn(a, b); }
__device__ __forceinline__ float fa(float a, float b) { return __fadd_rn(a, b); }
__device__ __forceinline__ float fs(float a, float b) { return __fsub_rn(a, b); }

__device__ __forceinline__ unsigned fkey(float f) {
  unsigned b = __float_as_uint(f);
  return (b & 0x80000000u) ? ~b : (b | 0x80000000u);
}
__device__ __forceinline__ float funkey(unsigned k) {
  unsigned b = (k & 0x80000000u) ? (k & 0x7FFFFFFFu) : ~k;
  return __uint_as_float(b);
}
__device__ __forceinline__ unsigned short bf16rne(float x) {
  unsigned b = __float_as_uint(x);
  return (unsigned short)((b + 0x7FFFu + ((b >> 16) & 1u)) >> 16);
}

// ---- numpy pairwise_sum (SSE2-npyv) of squares ----
__device__ float pairwise128_sq(const float* a) {
  float V[8][4];
#pragma unroll
  for (int j = 0; j < 8; ++j)
#pragma unroll
    for (int l = 0; l < 4; ++l) { float x = a[4 * j + l]; V[j][l] = fm(x, x); }
#pragma unroll
  for (int t = 1; t < 4; ++t)
#pragma unroll
    for (int j = 0; j < 8; ++j)
#pragma unroll
      for (int l = 0; l < 4; ++l) {
        float x = a[32 * t + 4 * j + l];
        V[j][l] = fa(V[j][l], fm(x, x));
      }
  float W[4];
#pragma unroll
  for (int l = 0; l < 4; ++l) {
    float p01 = fa(V[0][l], V[1][l]), p23 = fa(V[2][l], V[3][l]);
    float p45 = fa(V[4][l], V[5][l]), p67 = fa(V[6][l], V[7][l]);
    W[l] = fa(fa(p01, p23), fa(p45, p67));
  }
  return fa(fa(W[0], W[2]), fa(W[1], W[3]));
}
__device__ float pairwise256_sq(const float* a) {
  return fa(pairwise128_sq(a), pairwise128_sq(a + 128));
}

// ---- numpy einsum contig_two f32 dot (serial form, overflow fallback) ----
__device__ float dot256_np(const float* __restrict__ r, const float* __restrict__ c) {
  float L0 = 0.f, L1 = 0.f, L2 = 0.f, L3 = 0.f;
#pragma unroll 8
  for (int t = 0; t < 64; ++t) {
    float4 rv = *reinterpret_cast<const float4*>(r + 4 * t);
    float4 cv = *reinterpret_cast<const float4*>(c + 4 * t);
    L0 = fa(L0, fm(rv.x, cv.x));
    L1 = fa(L1, fm(rv.y, cv.y));
    L2 = fa(L2, fm(rv.z, cv.z));
    L3 = fa(L3, fm(rv.w, cv.w));
  }
  return fa(fa(L0, L2), fa(L1, L3));
}

__device__ __forceinline__ void np_eval(const float* __restrict__ rrow,
                                        const float* __restrict__ crow,
                                        float t1, float t3, int code,
                                        unsigned long long* __restrict__ dst) {
  float e = dot256_np(rrow, crow);
  float dn = fa(fs(t1, fa(e, e)), t3);
  atomicMin(dst, ((unsigned long long)fkey(dn) << 32) | (unsigned)code);
}

// ---- z: np-exact sequential chain per (m,d); 8 tokens/block, unrolled ----
__global__ __launch_bounds__(256) void k_z(const float* __restrict__ in,
                                           const float* __restrict__ w_in,
                                           float* __restrict__ residual) {
  const int m0 = blockIdx.x * 8;
  __shared__ float xs[8][FEAT];
  for (int i = threadIdx.x; i < 8 * FEAT; i += 256)
    xs[i / FEAT][i % FEAT] = in[(size_t)m0 * FEAT + i];
  __syncthreads();
  const int dg = threadIdx.x & 63;
  const int tg = threadIdx.x >> 6;
  float4 a0 = {0.f, 0.f, 0.f, 0.f}, a1 = {0.f, 0.f, 0.f, 0.f};
  for (int c = 0; c < 3; ++c) {
    const float* wbase = &w_in[(size_t)c * 252 * DIM + dg * 4];
    const float* xr0 = &xs[tg * 2 + 0][c];
    const float* xr1 = &xs[tg * 2 + 1][c];
#pragma unroll 12
    for (int f = 0; f < 252; ++f) {      // F = c*252+f ascending; chain order exact
      float4 w4 = *reinterpret_cast<const float4*>(&wbase[(size_t)f * DIM]);
      float x0 = xr0[f * 3];
      float x1 = xr1[f * 3];
      a0.x = fa(a0.x, fm(x0, w4.x)); a0.y = fa(a0.y, fm(x0, w4.y));
      a0.z = fa(a0.z, fm(x0, w4.z)); a0.w = fa(a0.w, fm(x0, w4.w));
      a1.x = fa(a1.x, fm(x1, w4.x)); a1.y = fa(a1.y, fm(x1, w4.y));
      a1.z = fa(a1.z, fm(x1, w4.z)); a1.w = fa(a1.w, fm(x1, w4.w));
    }
  }
  *reinterpret_cast<float4*>(&residual[(size_t)(m0 + tg * 2 + 0) * DIM + dg * 4]) = a0;
  *reinterpret_cast<float4*>(&residual[(size_t)(m0 + tg * 2 + 1) * DIM + dg * 4]) = a1;
}

// ---- codebook row norms (np pairwise) ----
__global__ __launch_bounds__(256) void k_cbnorm(const float* __restrict__ cb,
                                                float* __restrict__ cbn) {
  int row = blockIdx.x * 256 + threadIdx.x;
  if (row >= NQ * NCODE) return;
  cbn[row] = pairwise256_sq(&cb[(size_t)row * DIM]);
}

// ---- codebook f32 -> bf16 bits ----
__global__ __launch_bounds__(256) void k_cb16(const float* __restrict__ cb,
                                              unsigned short* __restrict__ cb16) {
  size_t i = (size_t)blockIdx.x * 1024 + (size_t)threadIdx.x * 4;
  float4 v = *reinterpret_cast<const float4*>(&cb[i]);
  ushort4 o;
  o.x = bf16rne(v.x); o.y = bf16rne(v.y); o.z = bf16rne(v.z); o.w = bf16rne(v.w);
  *reinterpret_cast<ushort4*>(&cb16[i]) = o;
}

// ---- w_out transpose -> bf16 wT16[768][256] ----
__global__ __launch_bounds__(256) void k_wt(const float* __restrict__ w_out,
                                            unsigned short* __restrict__ wT16) {
  int n = blockIdx.x, k = threadIdx.x;
  float v = (n < FEAT) ? w_out[(size_t)k * FEAT + n] : 0.f;
  wT16[(size_t)n * DIM + k] = bf16rne(v);
}

// ---- np token norms + best64 reset ----
__global__ __launch_bounds__(256) void k_t1(const float* __restrict__ residual,
                                            float* __restrict__ t1g,
                                            unsigned long long* __restrict__ best64) {
  int m = blockIdx.x * 256 + threadIdx.x;
  t1g[m] = pairwise256_sq(&residual[(size_t)m * DIM]);
  best64[m] = 0xFFFFFFFFFFFFFFFFull;
}

// ---- fused: MFMA screen (all 1024 codes) + LDS-compacted np repair + update ----
__global__ __launch_bounds__(256) void k_screen(
    const unsigned short* __restrict__ cb16, const float* __restrict__ cb,
    const float* __restrict__ cbn, float* __restrict__ residual,
    const float* __restrict__ t1g, unsigned long long* __restrict__ best64,
    float* __restrict__ allq, float* __restrict__ idxout, int q) {
  __shared__ __align__(16) unsigned short Bs[64][264];
  __shared__ float cbn_s[NCODE];
  __shared__ unsigned long long list[LCAP];
  __shared__ unsigned list2[L2CAP];
  __shared__ float fbs[64], t1_s[64], dlt_s[64];
  __shared__ unsigned lcnt, l2cnt;
  const int m0 = blockIdx.x * 64;
  const int tid = threadIdx.x, w = tid >> 6, lane = tid & 63;
  const int lrow = lane & 15, lk = lane >> 4;
  const unsigned short* cbq16 = cb16 + (size_t)q * NCODE * DIM;
  const float* cbqf = cb + (size_t)q * NCODE * DIM;

  for (int i = tid; i < NCODE; i += 256) cbn_s[i] = cbn[q * NCODE + i];
  if (tid < 64) {
    float t1 = t1g[m0 + tid];
    t1_s[tid] = t1;
    dlt_s[tid] = fmaxf(DSCALE * sqrtf(fmaxf(t1, 0.f)), 1e-5f);
  }
  if (tid == 0) { lcnt = 0; l2cnt = 0; }

  short8 afr[8];
  {
    const float* rrow = &residual[(size_t)(m0 + w * 16 + lrow) * DIM];
#pragma unroll
    for (int s = 0; s < 8; ++s) {
      float4 x0 = *reinterpret_cast<const float4*>(&rrow[s * 32 + lk * 8]);
      float4 x1 = *reinterpret_cast<const float4*>(&rrow[s * 32 + lk * 8 + 4]);
      short8 t;
      t[0] = (short)bf16rne(x0.x); t[1] = (short)bf16rne(x0.y);
      t[2] = (short)bf16rne(x0.z); t[3] = (short)bf16rne(x0.w);
      t[4] = (short)bf16rne(x1.x); t[5] = (short)bf16rne(x1.y);
      t[6] = (short)bf16rne(x1.z); t[7] = (short)bf16rne(x1.w);
      afr[s] = t;
    }
  }
  __syncthreads();

  const int tokbase = w * 16 + lk * 4;
  float dl[4];
#pragma unroll
  for (int r = 0; r < 4; ++r) dl[r] = dlt_s[tokbase + r];
  float runmin[4] = {FLT_MAX, FLT_MAX, FLT_MAX, FLT_MAX};
  int runcode[4] = {0, 0, 0, 0};

#define PUSH(PD, PC, R)                                                          \
  {                                                                              \
    unsigned idx_ = atomicAdd(&lcnt, 1u);                                        \
    unsigned lo_ = ((unsigned)(tokbase + (R)) << 10) | (unsigned)(PC);           \
    if (idx_ < LCAP)                                                             \
      list[idx_] = ((unsigned long long)fkey(PD) << 32) | lo_;                   \
    else                                                                         \
      np_eval(&residual[(size_t)(m0 + tokbase + (R)) * DIM],                     \
              &cbqf[(size_t)(PC) * DIM], t1_s[tokbase + (R)], cbn_s[(PC)],       \
              (PC), &best64[m0 + tokbase + (R)]);                                \
  }

  for (int ct = 0; ct < 16; ++ct) {
    __syncthreads();
    {
      int r = tid >> 2, seg = tid & 3;
      const uint4* src = reinterpret_cast<const uint4*>(
          &cbq16[(size_t)(ct * 64 + r) * DIM + seg * 64]);
      uint4* dst = reinterpret_cast<uint4*>(&Bs[r][seg * 64]);
#pragma unroll
      for (int u = 0; u < 8; ++u) dst[u] = src[u];
    }
    __syncthreads();

    f32x4 acc[4];
#pragma unroll
    for (int f = 0; f < 4; ++f) acc[f] = (f32x4){0.f, 0.f, 0.f, 0.f};
#pragma unroll
    for (int s = 0; s < 8; ++s) {
#pragma unroll
      for (int f = 0; f < 4; ++f) {
        short8 bfr = *reinterpret_cast<const short8*>(&Bs[f * 16 + lrow][s * 32 + lk * 8]);
        acc[f] = __builtin_amdgcn_mfma_f32_16x16x32_bf16(afr[s], bfr, acc[f], 0, 0, 0);
      }
    }

#pragma unroll
    for (int f = 0; f < 4; ++f) {
      const int code = ct * 64 + f * 16 + lrow;
      const float t3 = cbn_s[code];
#pragma unroll
      for (int r = 0; r < 4; ++r) {
        const float d = t3 - 2.0f * acc[f][r];
        if (d < runmin[r]) {
          if (runmin[r] <= d + dl[r]) PUSH(runmin[r], runcode[r], r);
          runmin[r] = d; runcode[r] = code;
        } else if (d <= runmin[r] + dl[r]) {
          PUSH(d, code, r);
        }
      }
    }
  }
#pragma unroll
  for (int r = 0; r < 4; ++r) PUSH(runmin[r], runcode[r], r);

  float fb[4] = {runmin[0], runmin[1], runmin[2], runmin[3]};
#pragma unroll
  for (int off = 8; off >= 1; off >>= 1)
#pragma unroll
    for (int r = 0; r < 4; ++r)
      fb[r] = fminf(fb[r], __shfl_xor(fb[r], off, 64));
  if (lrow == 0)
#pragma unroll
    for (int r = 0; r < 4; ++r) fbs[tokbase + r] = fb[r];
  __syncthreads();

  {
    unsigned n = lcnt; if (n > LCAP) n = LCAP;
    for (unsigned i = tid; i < n; i += 256) {
      unsigned long long e = list[i];
      unsigned lo = (unsigned)e;
      unsigned tok = (lo >> 10) & 63u;
      float df = funkey((unsigned)(e >> 32));
      if (df <= fbs[tok] + dlt_s[tok]) {
        unsigned j = atomicAdd(&l2cnt, 1u);
        if (j < L2CAP) list2[j] = lo & 0xFFFFu;
        else np_eval(&residual[(size_t)(m0 + tok) * DIM],
                     &cbqf[(size_t)(lo & 1023u) * DIM], t1_s[tok],
                     cbn_s[lo & 1023u], (int)(lo & 1023u), &best64[m0 + tok]);
      }
    }
  }
  __syncthreads();

  {
    unsigned n2 = l2cnt; if (n2 > L2CAP) n2 = L2CAP;
    const int j4 = lane & 3, g = lane >> 2;
    for (unsigned i0 = (unsigned)w * 16u; i0 < n2; i0 += 64u) {
      unsigned ci = i0 + (unsigned)g;
      bool act = ci < n2;
      unsigned ent = act ? list2[ci] : 0u;
      unsigned tok = (ent >> 10) & 63u, code = ent & 1023u;
      const float* rr = &residual[(size_t)(m0 + tok) * DIM];
      const float* cc = &cbqf[(size_t)code * DIM];
      float L = 0.f;
#pragma unroll 8
      for (int t = 0; t < 64; ++t)
        L = fa(L, fm(rr[4 * t + j4], cc[4 * t + j4]));
      float tmp = fa(L, __shfl_xor(L, 2, 64));
      float e4 = fa(tmp, __shfl_xor(tmp, 1, 64));
      if (act && j4 == 0) {
        float dn = fa(fs(t1_s[tok], fa(e4, e4)), cbn_s[code]);
        atomicMin(&best64[m0 + tok],
                  ((unsigned long long)fkey(dn) << 32) | code);
      }
    }
  }
  __syncthreads();

  // fused update: residual step (np fs), allq, idx — 16 tokens per wave
  for (int t = 0; t < 16; ++t) {
    const int tok = w * 16 + t;
    const size_t m = (size_t)m0 + tok;
    const int ci = (int)(best64[m] & 0xFFFFFFFFull);
    const float4 cv = *reinterpret_cast<const float4*>(&cbqf[(size_t)ci * DIM + lane * 4]);
    const size_t base = m * DIM + lane * 4;
    float4 r = *reinterpret_cast<const float4*>(&residual[base]);
    r.x = fs(r.x, cv.x); r.y = fs(r.y, cv.y); r.z = fs(r.z, cv.z); r.w = fs(r.w, cv.w);
    *reinterpret_cast<float4*>(&residual[base]) = r;
    *reinterpret_cast<float4*>(&allq[((size_t)q * M_TOK + m) * DIM + lane * 4]) = cv;
    if (lane == 0) idxout[m * NQ + q] = (float)ci;
  }
#undef PUSH
}

// ---- quantized = relu( (sum_q allq) @ w_out ), MFMA bf16; one block = 64 tokens ----
__global__ __launch_bounds__(256) void k_gemm_out(const float* __restrict__ allq,
                                                  const unsigned short* __restrict__ wT16,
                                                  float* __restrict__ C) {
  __shared__ __align__(16) unsigned short As[64][264];
  __shared__ __align__(16) unsigned short Bs[64][264];
  const int m0 = blockIdx.x * 64;
  const int tid = threadIdx.x, w = tid >> 6, lane = tid & 63;
  const int lrow = lane & 15, lk = lane >> 4;

  // stage A = sum_q allq (f32, q-ascending) -> bf16 tile. Coalesced flat striping.
#pragma unroll
  for (int k4 = 0; k4 < 16; ++k4) {
    int f4 = tid + k4 * 256;           // 0..4095 float4s of the 64x256 tile
    int tok = f4 >> 6, dseg = f4 & 63;
    float4 v = {0.f, 0.f, 0.f, 0.f};
#pragma unroll
    for (int qq = 0; qq < NQ; ++qq) {
      float4 t = *reinterpret_cast<const float4*>(
          &allq[((size_t)qq * M_TOK + m0 + tok) * DIM + dseg * 4]);
      v.x = fa(v.x, t.x); v.y = fa(v.y, t.y); v.z = fa(v.z, t.z); v.w = fa(v.w, t.w);
    }
    ushort4 o;
    o.x = bf16rne(v.x); o.y = bf16rne(v.y); o.z = bf16rne(v.z); o.w = bf16rne(v.w);
    *reinterpret_cast<ushort4*>(&As[tok][dseg * 4]) = o;
  }
  __syncthreads();

  short8 afr[8];
#pragma unroll
  for (int s = 0; s < 8; ++s)
    afr[s] = *reinterpret_cast<const short8*>(&As[w * 16 + lrow][s * 32 + lk * 8]);

  for (int nt = 0; nt < 12; ++nt) {
    const int n0 = nt * 64;
    __syncthreads();
    {
      int r = tid >> 2, seg = tid & 3;
      const uint4* src = reinterpret_cast<const uint4*>(&wT16[(size_t)(n0 + r) * DIM + seg * 64]);
      uint4* dst = reinterpret_cast<uint4*>(&Bs[r][seg * 64]);
#pragma unroll
      for (int u = 0; u < 8; ++u) dst[u] = src[u];
    }
    __syncthreads();

    f32x4 acc[4];
#pragma unroll
    for (int f = 0; f < 4; ++f) acc[f] = (f32x4){0.f, 0.f, 0.f, 0.f};
#pragma unroll
    for (int s = 0; s < 8; ++s) {
#pragma unroll
      for (int f = 0; f < 4; ++f) {
        short8 bfr = *reinterpret_cast<const short8*>(&Bs[f * 16 + lrow][s * 32 + lk * 8]);
        acc[f] = __builtin_amdgcn_mfma_f32_16x16x32_bf16(afr[s], bfr, acc[f], 0, 0, 0);
      }
    }

#pragma unroll
    for (int f = 0; f < 4; ++f) {
      const int col = n0 + f * 16 + lrow;
      if (col < FEAT) {
#pragma unroll
        for (int r = 0; r < 4; ++r)
          C[(size_t)(m0 + w * 16 + lk * 4 + r) * FEAT + col] = fmaxf(acc[f][r], 0.f);
      }
    }
  }
}

extern "C" void kernel_launch(void* const* d_in, const int* in_sizes, int n_in,
                              void* d_out, int out_size, void* d_ws, size_t ws_size,
                              hipStream_t stream) {
  int i_inputs = 0, i_cb = 1, iA = 2, iB = 3;
  {
    int a = -1, b = -1, ii = -1, ic = -1;
    for (int i = 0; i < n_in; ++i) {
      if (in_sizes[i] == M_TOK * FEAT) ii = i;
      else if (in_sizes[i] == NQ * NCODE * DIM) ic = i;
      else if (in_sizes[i] == FEAT * DIM) { if (a < 0) a = i; else b = i; }
    }
    if (ii >= 0 && ic >= 0 && a >= 0 && b >= 0) { i_inputs = ii; i_cb = ic; iA = a; iB = b; }
  }
  const float* inputs = (const float*)d_in[i_inputs];
  const float* cb     = (const float*)d_in[i_cb];
  const float* w_in   = (const float*)d_in[iA];
  const float* w_out  = (const float*)d_in[iB];

  float* out       = (float*)d_out;
  float* quantized = out;                                 // 16384*756
  float* allq      = out + (size_t)M_TOK * FEAT;          // 8*16384*256
  float* idxout    = allq + (size_t)NQ * M_TOK * DIM;     // 16384*8

  // residual (16.8MB) lives in the quantized region (dead before k_gemm_out).
  float* residual = quantized;

  // Small scratch in d_ws (~4.8 MB). k_gemm_out reads only allq (output) + wT16 (ws).
  char* ws = (char*)d_ws;
  unsigned short*     cb16   = (unsigned short*)(ws);                 // 4,194,304 B
  unsigned short*     wT16   = (unsigned short*)(ws + 4194304);       //   393,216 B
  float*              cbn    = (float*)(ws + 4587520);                //    32,768 B
  float*              t1g    = (float*)(ws + 4620288);                //    65,536 B
  unsigned long long* best64 = (unsigned long long*)(ws + 4685824);   //   131,072 B

  k_z<<<M_TOK / 8, 256, 0, stream>>>(inputs, w_in, residual);
  k_cbnorm<<<NQ * NCODE / 256, 256, 0, stream>>>(cb, cbn);
  k_cb16<<<NQ * NCODE * DIM / 1024, 256, 0, stream>>>(cb, cb16);
  k_wt<<<768, 256, 0, stream>>>(w_out, wT16);
  k_t1<<<M_TOK / 256, 256, 0, stream>>>(residual, t1g, best64);
  for (int q = 0; q < NQ; ++q) {
    k_screen<<<M_TOK / 64, 256, 0, stream>>>(cb16, cb, cbn, residual, t1g, best64,
                                             allq, idxout, q);
    if (q < NQ - 1)
      k_t1<<<M_TOK / 256, 256, 0, stream>>>(residual, t1g, best64);
  }
  k_gemm_out<<<M_TOK / 64, 256, 0, stream>>>(allq, wT16, quantized);
}

// Round 13
// 792.281 us; speedup vs baseline: 19.1505x; 1.2740x over previous
//
#include <hip/hip_runtime.h>
#include <float.h>

#define M_TOK 16384   // B*T
#define DIM   256
#define NCODE 1024
#define NQ    8
#define FEAT  756
#define DSCALE 0.00375f   // DELTA = DSCALE*sqrt(t1): == 0.06 at q=0, ~23 sigma of bf16 noise
#define LCAP  6144
#define L2CAP 512

using short8 = __attribute__((ext_vector_type(8))) short;  // 8 bf16
using f32x4  = __attribute__((ext_vector_type(4))) float;

__device__ __forceinline__ float fm(float a, float b) { return __fmul_rn(a, b); }
__device__ __forceinline__ float fa(float a, float b) { return __fadd_rn(a, b); }
__device__ __forceinline__ float fs(float a, float b) { return __fsub_rn(a, b); }

__device__ __forceinline__ unsigned fkey(float f) {
  unsigned b = __float_as_uint(f);
  return (b & 0x80000000u) ? ~b : (b | 0x80000000u);
}
__device__ __forceinline__ float funkey(unsigned k) {
  unsigned b = (k & 0x80000000u) ? (k & 0x7FFFFFFFu) : ~k;
  return __uint_as_float(b);
}
__device__ __forceinline__ unsigned short bf16rne(float x) {
  unsigned b = __float_as_uint(x);
  return (unsigned short)((b + 0x7FFFu + ((b >> 16) & 1u)) >> 16);
}

// ---- numpy pairwise_sum (SSE2-npyv) of squares ----
__device__ float pairwise128_sq(const float* a) {
  float V[8][4];
#pragma unroll
  for (int j = 0; j < 8; ++j)
#pragma unroll
    for (int l = 0; l < 4; ++l) { float x = a[4 * j + l]; V[j][l] = fm(x, x); }
#pragma unroll
  for (int t = 1; t < 4; ++t)
#pragma unroll
    for (int j = 0; j < 8; ++j)
#pragma unroll
      for (int l = 0; l < 4; ++l) {
        float x = a[32 * t + 4 * j + l];
        V[j][l] = fa(V[j][l], fm(x, x));
      }
  float W[4];
#pragma unroll
  for (int l = 0; l < 4; ++l) {
    float p01 = fa(V[0][l], V[1][l]), p23 = fa(V[2][l], V[3][l]);
    float p45 = fa(V[4][l], V[5][l]), p67 = fa(V[6][l], V[7][l]);
    W[l] = fa(fa(p01, p23), fa(p45, p67));
  }
  return fa(fa(W[0], W[2]), fa(W[1], W[3]));
}
__device__ float pairwise256_sq(const float* a) {
  return fa(pairwise128_sq(a), pairwise128_sq(a + 128));
}

// ---- numpy einsum contig_two f32 dot (serial form, overflow fallback) ----
__device__ float dot256_np(const float* __restrict__ r, const float* __restrict__ c) {
  float L0 = 0.f, L1 = 0.f, L2 = 0.f, L3 = 0.f;
#pragma unroll 8
  for (int t = 0; t < 64; ++t) {
    float4 rv = *reinterpret_cast<const float4*>(r + 4 * t);
    float4 cv = *reinterpret_cast<const float4*>(c + 4 * t);
    L0 = fa(L0, fm(rv.x, cv.x));
    L1 = fa(L1, fm(rv.y, cv.y));
    L2 = fa(L2, fm(rv.z, cv.z));
    L3 = fa(L3, fm(rv.w, cv.w));
  }
  return fa(fa(L0, L2), fa(L1, L3));
}

__device__ __forceinline__ void np_eval(const float* __restrict__ rrow,
                                        const float* __restrict__ crow,
                                        float t1, float t3, int code,
                                        unsigned long long* __restrict__ dst) {
  float e = dot256_np(rrow, crow);
  float dn = fa(fs(t1, fa(e, e)), t3);
  atomicMin(dst, ((unsigned long long)fkey(dn) << 32) | (unsigned)code);
}

// ---- z: np-exact sequential chain per (m,d); 8 tokens/block, 6-wide load batches ----
__global__ __launch_bounds__(256) void k_z(const float* __restrict__ in,
                                           const float* __restrict__ w_in,
                                           float* __restrict__ residual) {
  const int m0 = blockIdx.x * 8;
  __shared__ float xs[8][FEAT];
  for (int i = threadIdx.x; i < 8 * FEAT; i += 256)
    xs[i / FEAT][i % FEAT] = in[(size_t)m0 * FEAT + i];
  __syncthreads();
  const int dg = threadIdx.x & 63;
  const int tg = threadIdx.x >> 6;
  float4 a0 = {0.f, 0.f, 0.f, 0.f}, a1 = {0.f, 0.f, 0.f, 0.f};
  for (int c = 0; c < 3; ++c) {
    const float* wbase = &w_in[(size_t)c * 252 * DIM + dg * 4];
    const float* xr0 = &xs[tg * 2 + 0][c];
    const float* xr1 = &xs[tg * 2 + 1][c];
    for (int fb = 0; fb < 252; fb += 6) {      // 6 independent loads per batch
      float4 wv[6];
#pragma unroll
      for (int j = 0; j < 6; ++j)
        wv[j] = *reinterpret_cast<const float4*>(&wbase[(size_t)(fb + j) * DIM]);
#pragma unroll
      for (int j = 0; j < 6; ++j) {            // chain order F-ascending, exact
        float x0 = xr0[(fb + j) * 3];
        float x1 = xr1[(fb + j) * 3];
        a0.x = fa(a0.x, fm(x0, wv[j].x)); a0.y = fa(a0.y, fm(x0, wv[j].y));
        a0.z = fa(a0.z, fm(x0, wv[j].z)); a0.w = fa(a0.w, fm(x0, wv[j].w));
        a1.x = fa(a1.x, fm(x1, wv[j].x)); a1.y = fa(a1.y, fm(x1, wv[j].y));
        a1.z = fa(a1.z, fm(x1, wv[j].z)); a1.w = fa(a1.w, fm(x1, wv[j].w));
      }
    }
  }
  *reinterpret_cast<float4*>(&residual[(size_t)(m0 + tg * 2 + 0) * DIM + dg * 4]) = a0;
  *reinterpret_cast<float4*>(&residual[(size_t)(m0 + tg * 2 + 1) * DIM + dg * 4]) = a1;
}

// ---- codebook row norms (np pairwise) ----
__global__ __launch_bounds__(256) void k_cbnorm(const float* __restrict__ cb,
                                                float* __restrict__ cbn) {
  int row = blockIdx.x * 256 + threadIdx.x;
  if (row >= NQ * NCODE) return;
  cbn[row] = pairwise256_sq(&cb[(size_t)row * DIM]);
}

// ---- codebook f32 -> bf16 bits ----
__global__ __launch_bounds__(256) void k_cb16(const float* __restrict__ cb,
                                              unsigned short* __restrict__ cb16) {
  size_t i = (size_t)blockIdx.x * 1024 + (size_t)threadIdx.x * 4;
  float4 v = *reinterpret_cast<const float4*>(&cb[i]);
  ushort4 o;
  o.x = bf16rne(v.x); o.y = bf16rne(v.y); o.z = bf16rne(v.z); o.w = bf16rne(v.w);
  *reinterpret_cast<ushort4*>(&cb16[i]) = o;
}

// ---- w_out transpose -> bf16 wT16[768][256] ----
__global__ __launch_bounds__(256) void k_wt(const float* __restrict__ w_out,
                                            unsigned short* __restrict__ wT16) {
  int n = blockIdx.x, k = threadIdx.x;
  float v = (n < FEAT) ? w_out[(size_t)k * FEAT + n] : 0.f;
  wT16[(size_t)n * DIM + k] = bf16rne(v);
}

// ---- np token norms + best64 reset (launched ONCE, before q=0) ----
__global__ __launch_bounds__(256) void k_t1(const float* __restrict__ residual,
                                            float* __restrict__ t1g,
                                            unsigned long long* __restrict__ best64) {
  int m = blockIdx.x * 256 + threadIdx.x;
  t1g[m] = pairwise256_sq(&residual[(size_t)m * DIM]);
  best64[m] = 0xFFFFFFFFFFFFFFFFull;
}

// ---- fused: 8-wave MFMA screen + LDS repair + update + next-t1 ----
__global__ __launch_bounds__(512) void k_screen(
    const unsigned short* __restrict__ cb16, const float* __restrict__ cb,
    const float* __restrict__ cbn, float* __restrict__ residual,
    float* __restrict__ t1g, unsigned long long* __restrict__ best64,
    float* __restrict__ allq, float* __restrict__ idxout, int q) {
  // Bs (2 x 64 x 264 shorts = 67584B) overlaid with rsnew (64 x 265 f32 = 67840B)
  __shared__ __align__(16) char smem[67840];
  __shared__ float cbn_s[NCODE];
  __shared__ unsigned long long list[LCAP];
  __shared__ unsigned list2[L2CAP];
  __shared__ unsigned fbs_u[64];
  __shared__ float t1_s[64], dlt_s[64];
  __shared__ unsigned lcnt, l2cnt;
  unsigned short (*Bs0)[264] = reinterpret_cast<unsigned short(*)[264]>(smem);
  unsigned short (*Bs1)[264] = reinterpret_cast<unsigned short(*)[264]>(smem + 33792);
  float* rsnew = reinterpret_cast<float*>(smem);   // [64][265], stride 265

  const int m0 = blockIdx.x * 64;
  const int tid = threadIdx.x, w = tid >> 6, lane = tid & 63;
  const int lrow = lane & 15, lk = lane >> 4;
  const int grp = w >> 2, wg = w & 3;              // ct-half, token-quarter
  const unsigned short* cbq16 = cb16 + (size_t)q * NCODE * DIM;
  const float* cbqf = cb + (size_t)q * NCODE * DIM;

  for (int i = tid; i < NCODE; i += 512) cbn_s[i] = cbn[q * NCODE + i];
  if (tid < 64) {
    float t1 = t1g[m0 + tid];
    t1_s[tid] = t1;
    dlt_s[tid] = fmaxf(DSCALE * sqrtf(fmaxf(t1, 0.f)), 1e-5f);
    fbs_u[tid] = 0xFFFFFFFFu;
  }
  if (tid == 0) { lcnt = 0; l2cnt = 0; }

  // A fragments: token = m0 + wg*16 + lrow (groups duplicate A loads)
  short8 afr[8];
  {
    const float* rrow = &residual[(size_t)(m0 + wg * 16 + lrow) * DIM];
#pragma unroll
    for (int s = 0; s < 8; ++s) {
      float4 x0 = *reinterpret_cast<const float4*>(&rrow[s * 32 + lk * 8]);
      float4 x1 = *reinterpret_cast<const float4*>(&rrow[s * 32 + lk * 8 + 4]);
      short8 t;
      t[0] = (short)bf16rne(x0.x); t[1] = (short)bf16rne(x0.y);
      t[2] = (short)bf16rne(x0.z); t[3] = (short)bf16rne(x0.w);
      t[4] = (short)bf16rne(x1.x); t[5] = (short)bf16rne(x1.y);
      t[6] = (short)bf16rne(x1.z); t[7] = (short)bf16rne(x1.w);
      afr[s] = t;
    }
  }
  __syncthreads();

  const int tokbase = wg * 16 + lk * 4;
  float dl[4];
#pragma unroll
  for (int r = 0; r < 4; ++r) dl[r] = dlt_s[tokbase + r];
  float runmin[4] = {FLT_MAX, FLT_MAX, FLT_MAX, FLT_MAX};
  int runcode[4] = {0, 0, 0, 0};

#define PUSH(PD, PC, R)                                                          \
  {                                                                              \
    unsigned idx_ = atomicAdd(&lcnt, 1u);                                        \
    unsigned lo_ = ((unsigned)(tokbase + (R)) << 10) | (unsigned)(PC);           \
    if (idx_ < LCAP)                                                             \
      list[idx_] = ((unsigned long long)fkey(PD) << 32) | lo_;                   \
    else                                                                         \
      np_eval(&residual[(size_t)(m0 + tokbase + (R)) * DIM],                     \
              &cbqf[(size_t)(PC) * DIM], t1_s[tokbase + (R)], cbn_s[(PC)],       \
              (PC), &best64[m0 + tokbase + (R)]);                                \
  }

  for (int cc = 0; cc < 8; ++cc) {
    {  // stage both groups' tiles: rows 0-63 -> Bs0 (ct=cc), 64-127 -> Bs1 (ct=cc+8)
      int r = tid >> 2, seg = tid & 3;
      int code = (r < 64) ? (cc * 64 + r) : ((cc + 8) * 64 + (r - 64));
      const uint4* src = reinterpret_cast<const uint4*>(
          &cbq16[(size_t)code * DIM + seg * 64]);
      unsigned short* dstrow = (r < 64) ? Bs0[r] : Bs1[r - 64];
      uint4* dst = reinterpret_cast<uint4*>(&dstrow[seg * 64]);
#pragma unroll
      for (int u = 0; u < 8; ++u) dst[u] = src[u];
    }
    __syncthreads();

    unsigned short (*Bsg)[264] = grp ? Bs1 : Bs0;
    f32x4 acc[4];
#pragma unroll
    for (int f = 0; f < 4; ++f) acc[f] = (f32x4){0.f, 0.f, 0.f, 0.f};
#pragma unroll
    for (int s = 0; s < 8; ++s) {
#pragma unroll
      for (int f = 0; f < 4; ++f) {
        short8 bfr = *reinterpret_cast<const short8*>(&Bsg[f * 16 + lrow][s * 32 + lk * 8]);
        acc[f] = __builtin_amdgcn_mfma_f32_16x16x32_bf16(afr[s], bfr, acc[f], 0, 0, 0);
      }
    }

    const int cbase_g = (cc + 8 * grp) * 64;
#pragma unroll
    for (int f = 0; f < 4; ++f) {
      const int code = cbase_g + f * 16 + lrow;
      const float t3 = cbn_s[code];
#pragma unroll
      for (int r = 0; r < 4; ++r) {
        const float d = t3 - 2.0f * acc[f][r];
        if (d < runmin[r]) {
          if (runmin[r] <= d + dl[r]) PUSH(runmin[r], runcode[r], r);
          runmin[r] = d; runcode[r] = code;
        } else if (d <= runmin[r] + dl[r]) {
          PUSH(d, code, r);
        }
      }
    }
    __syncthreads();
  }
#pragma unroll
  for (int r = 0; r < 4; ++r) PUSH(runmin[r], runcode[r], r);

  // per-token fast best: reduce across 16 lrow lanes, combine groups via LDS keys
  float fb[4] = {runmin[0], runmin[1], runmin[2], runmin[3]};
#pragma unroll
  for (int off = 8; off >= 1; off >>= 1)
#pragma unroll
    for (int r = 0; r < 4; ++r)
      fb[r] = fminf(fb[r], __shfl_xor(fb[r], off, 64));
  if (lrow == 0)
#pragma unroll
    for (int r = 0; r < 4; ++r)
      atomicMin(&fbs_u[tokbase + r], fkey(fb[r]));
  __syncthreads();

  // filter list -> survivors within DELTA of the combined fast best
  {
    unsigned n = lcnt; if (n > LCAP) n = LCAP;
    for (unsigned i = tid; i < n; i += 512) {
      unsigned long long e = list[i];
      unsigned lo = (unsigned)e;
      unsigned tok = (lo >> 10) & 63u;
      float df = funkey((unsigned)(e >> 32));
      if (df <= funkey(fbs_u[tok]) + dlt_s[tok]) {
        unsigned j = atomicAdd(&l2cnt, 1u);
        if (j < L2CAP) list2[j] = lo & 0xFFFFu;
        else np_eval(&residual[(size_t)(m0 + tok) * DIM],
                     &cbqf[(size_t)(lo & 1023u) * DIM], t1_s[tok],
                     cbn_s[lo & 1023u], (int)(lo & 1023u), &best64[m0 + tok]);
      }
    }
  }
  __syncthreads();

  // cooperative np-exact repair: 4 lanes per candidate, 16/wave, 8 waves
  {
    unsigned n2 = l2cnt; if (n2 > L2CAP) n2 = L2CAP;
    const int j4 = lane & 3, g = lane >> 2;
    for (unsigned i0 = (unsigned)w * 16u; i0 < n2; i0 += 128u) {
      unsigned ci = i0 + (unsigned)g;
      bool act = ci < n2;
      unsigned ent = act ? list2[ci] : 0u;
      unsigned tok = (ent >> 10) & 63u, code = ent & 1023u;
      const float* rr = &residual[(size_t)(m0 + tok) * DIM];
      const float* cc2 = &cbqf[(size_t)code * DIM];
      float L = 0.f;
#pragma unroll 8
      for (int t = 0; t < 64; ++t)
        L = fa(L, fm(rr[4 * t + j4], cc2[4 * t + j4]));
      float tmp = fa(L, __shfl_xor(L, 2, 64));
      float e4 = fa(tmp, __shfl_xor(tmp, 1, 64));
      if (act && j4 == 0) {
        float dn = fa(fs(t1_s[tok], fa(e4, e4)), cbn_s[code]);
        atomicMin(&best64[m0 + tok],
                  ((unsigned long long)fkey(dn) << 32) | code);
      }
    }
  }
  __syncthreads();

  // update: residual step (np fs), allq, idx; stash new row in LDS for t1
  for (int t = 0; t < 8; ++t) {
    const int tok = w * 8 + t;
    const size_t m = (size_t)m0 + tok;
    const int ci = (int)(best64[m] & 0xFFFFFFFFull);
    const float4 cv = *reinterpret_cast<const float4*>(&cbqf[(size_t)ci * DIM + lane * 4]);
    const size_t base = m * DIM + lane * 4;
    float4 r = *reinterpret_cast<const float4*>(&residual[base]);
    r.x = fs(r.x, cv.x); r.y = fs(r.y, cv.y); r.z = fs(r.z, cv.z); r.w = fs(r.w, cv.w);
    *reinterpret_cast<float4*>(&residual[base]) = r;
    float* rd = &rsnew[(size_t)tok * 265 + lane * 4];
    rd[0] = r.x; rd[1] = r.y; rd[2] = r.z; rd[3] = r.w;
    *reinterpret_cast<float4*>(&allq[((size_t)q * M_TOK + m) * DIM + lane * 4]) = cv;
    if (lane == 0) idxout[m * NQ + q] = (float)ci;
  }
  __syncthreads();

  // fused next-step t1 (np pairwise on updated row) + best64 reset
  if (tid < 64) {
    t1g[m0 + tid] = pairwise256_sq(&rsnew[(size_t)tid * 265]);
    best64[m0 + tid] = 0xFFFFFFFFFFFFFFFFull;
  }
#undef PUSH
}

// ---- quantized = relu( (sum_q allq) @ w_out ), MFMA bf16; one block = 64 tokens ----
__global__ __launch_bounds__(256) void k_gemm_out(const float* __restrict__ allq,
                                                  const unsigned short* __restrict__ wT16,
                                                  float* __restrict__ C) {
  __shared__ __align__(16) unsigned short As[64][264];
  __shared__ __align__(16) unsigned short Bs[64][264];
  const int m0 = blockIdx.x * 64;
  const int tid = threadIdx.x, w = tid >> 6, lane = tid & 63;
  const int lrow = lane & 15, lk = lane >> 4;

#pragma unroll
  for (int k4 = 0; k4 < 16; ++k4) {
    int f4 = tid + k4 * 256;
    int tok = f4 >> 6, dseg = f4 & 63;
    float4 v = {0.f, 0.f, 0.f, 0.f};
#pragma unroll
    for (int qq = 0; qq < NQ; ++qq) {
      float4 t = *reinterpret_cast<const float4*>(
          &allq[((size_t)qq * M_TOK + m0 + tok) * DIM + dseg * 4]);
      v.x = fa(v.x, t.x); v.y = fa(v.y, t.y); v.z = fa(v.z, t.z); v.w = fa(v.w, t.w);
    }
    ushort4 o;
    o.x = bf16rne(v.x); o.y = bf16rne(v.y); o.z = bf16rne(v.z); o.w = bf16rne(v.w);
    *reinterpret_cast<ushort4*>(&As[tok][dseg * 4]) = o;
  }
  __syncthreads();

  short8 afr[8];
#pragma unroll
  for (int s = 0; s < 8; ++s)
    afr[s] = *reinterpret_cast<const short8*>(&As[w * 16 + lrow][s * 32 + lk * 8]);

  for (int nt = 0; nt < 12; ++nt) {
    const int n0 = nt * 64;
    __syncthreads();
    {
      int r = tid >> 2, seg = tid & 3;
      const uint4* src = reinterpret_cast<const uint4*>(&wT16[(size_t)(n0 + r) * DIM + seg * 64]);
      uint4* dst = reinterpret_cast<uint4*>(&Bs[r][seg * 64]);
#pragma unroll
      for (int u = 0; u < 8; ++u) dst[u] = src[u];
    }
    __syncthreads();

    f32x4 acc[4];
#pragma unroll
    for (int f = 0; f < 4; ++f) acc[f] = (f32x4){0.f, 0.f, 0.f, 0.f};
#pragma unroll
    for (int s = 0; s < 8; ++s) {
#pragma unroll
      for (int f = 0; f < 4; ++f) {
        short8 bfr = *reinterpret_cast<const short8*>(&Bs[f * 16 + lrow][s * 32 + lk * 8]);
        acc[f] = __builtin_amdgcn_mfma_f32_16x16x32_bf16(afr[s], bfr, acc[f], 0, 0, 0);
      }
    }

#pragma unroll
    for (int f = 0; f < 4; ++f) {
      const int col = n0 + f * 16 + lrow;
      if (col < FEAT) {
#pragma unroll
        for (int r = 0; r < 4; ++r)
          C[(size_t)(m0 + w * 16 + lk * 4 + r) * FEAT + col] = fmaxf(acc[f][r], 0.f);
      }
    }
  }
}

extern "C" void kernel_launch(void* const* d_in, const int* in_sizes, int n_in,
                              void* d_out, int out_size, void* d_ws, size_t ws_size,
                              hipStream_t stream) {
  int i_inputs = 0, i_cb = 1, iA = 2, iB = 3;
  {
    int a = -1, b = -1, ii = -1, ic = -1;
    for (int i = 0; i < n_in; ++i) {
      if (in_sizes[i] == M_TOK * FEAT) ii = i;
      else if (in_sizes[i] == NQ * NCODE * DIM) ic = i;
      else if (in_sizes[i] == FEAT * DIM) { if (a < 0) a = i; else b = i; }
    }
    if (ii >= 0 && ic >= 0 && a >= 0 && b >= 0) { i_inputs = ii; i_cb = ic; iA = a; iB = b; }
  }
  const float* inputs = (const float*)d_in[i_inputs];
  const float* cb     = (const float*)d_in[i_cb];
  const float* w_in   = (const float*)d_in[iA];
  const float* w_out  = (const float*)d_in[iB];

  float* out       = (float*)d_out;
  float* quantized = out;                                 // 16384*756
  float* allq      = out + (size_t)M_TOK * FEAT;          // 8*16384*256
  float* idxout    = allq + (size_t)NQ * M_TOK * DIM;     // 16384*8

  // residual (16.8MB) lives in the quantized region (dead before k_gemm_out).
  float* residual = quantized;

  // Small scratch in d_ws (~4.8 MB). k_gemm_out reads only allq (output) + wT16 (ws).
  char* ws = (char*)d_ws;
  unsigned short*     cb16   = (unsigned short*)(ws);                 // 4,194,304 B
  unsigned short*     wT16   = (unsigned short*)(ws + 4194304);       //   393,216 B
  float*              cbn    = (float*)(ws + 4587520);                //    32,768 B
  float*              t1g    = (float*)(ws + 4620288);                //    65,536 B
  unsigned long long* best64 = (unsigned long long*)(ws + 4685824);   //   131,072 B

  k_z<<<M_TOK / 8, 256, 0, stream>>>(inputs, w_in, residual);
  k_cbnorm<<<NQ * NCODE / 256, 256, 0, stream>>>(cb, cbn);
  k_cb16<<<NQ * NCODE * DIM / 1024, 256, 0, stream>>>(cb, cb16);
  k_wt<<<768, 256, 0, stream>>>(w_out, wT16);
  k_t1<<<M_TOK / 256, 256, 0, stream>>>(residual, t1g, best64);
  for (int q = 0; q < NQ; ++q)
    k_screen<<<M_TOK / 64, 512, 0, stream>>>(cb16, cb, cbn, residual, t1g, best64,
                                             allq, idxout, q);
  k_gemm_out<<<M_TOK / 64, 256, 0, stream>>>(allq, wT16, quantized);
}

// Round 14
// 784.890 us; speedup vs baseline: 19.3308x; 1.0094x over previous
//
#include <hip/hip_runtime.h>
#include <float.h>

#define M_TOK 16384   // B*T
#define DIM   256
#define NCODE 1024
#define NQ    8
#define FEAT  756
#define DSCALE 0.00375f   // DELTA = DSCALE*sqrt(t1): == 0.06 at q=0, ~23 sigma of bf16 noise
#define LCAP  2560
#define L2CAP 512

using short8 = __attribute__((ext_vector_type(8))) short;  // 8 bf16
using f32x4  = __attribute__((ext_vector_type(4))) float;

__device__ __forceinline__ float fm(float a, float b) { return __fmul_rn(a, b); }
__device__ __forceinline__ float fa(float a, float b) { return __fadd_rn(a, b); }
__device__ __forceinline__ float fs(float a, float b) { return __fsub_rn(a, b); }

__device__ __forceinline__ unsigned fkey(float f) {
  unsigned b = __float_as_uint(f);
  return (b & 0x80000000u) ? ~b : (b | 0x80000000u);
}
__device__ __forceinline__ float funkey(unsigned k) {
  unsigned b = (k & 0x80000000u) ? (k & 0x7FFFFFFFu) : ~k;
  return __uint_as_float(b);
}
__device__ __forceinline__ unsigned short bf16rne(float x) {
  unsigned b = __float_as_uint(x);
  return (unsigned short)((b + 0x7FFFu + ((b >> 16) & 1u)) >> 16);
}

// ---- numpy pairwise_sum (SSE2-npyv) of squares ----
__device__ float pairwise128_sq(const float* a) {
  float V[8][4];
#pragma unroll
  for (int j = 0; j < 8; ++j)
#pragma unroll
    for (int l = 0; l < 4; ++l) { float x = a[4 * j + l]; V[j][l] = fm(x, x); }
#pragma unroll
  for (int t = 1; t < 4; ++t)
#pragma unroll
    for (int j = 0; j < 8; ++j)
#pragma unroll
      for (int l = 0; l < 4; ++l) {
        float x = a[32 * t + 4 * j + l];
        V[j][l] = fa(V[j][l], fm(x, x));
      }
  float W[4];
#pragma unroll
  for (int l = 0; l < 4; ++l) {
    float p01 = fa(V[0][l], V[1][l]), p23 = fa(V[2][l], V[3][l]);
    float p45 = fa(V[4][l], V[5][l]), p67 = fa(V[6][l], V[7][l]);
    W[l] = fa(fa(p01, p23), fa(p45, p67));
  }
  return fa(fa(W[0], W[2]), fa(W[1], W[3]));
}
__device__ float pairwise256_sq(const float* a) {
  return fa(pairwise128_sq(a), pairwise128_sq(a + 128));
}

// ---- numpy einsum contig_two f32 dot (serial form, overflow fallback) ----
__device__ float dot256_np(const float* __restrict__ r, const float* __restrict__ c) {
  float L0 = 0.f, L1 = 0.f, L2 = 0.f, L3 = 0.f;
#pragma unroll 8
  for (int t = 0; t < 64; ++t) {
    float4 rv = *reinterpret_cast<const float4*>(r + 4 * t);
    float4 cv = *reinterpret_cast<const float4*>(c + 4 * t);
    L0 = fa(L0, fm(rv.x, cv.x));
    L1 = fa(L1, fm(rv.y, cv.y));
    L2 = fa(L2, fm(rv.z, cv.z));
    L3 = fa(L3, fm(rv.w, cv.w));
  }
  return fa(fa(L0, L2), fa(L1, L3));
}

__device__ __forceinline__ void np_eval(const float* __restrict__ rrow,
                                        const float* __restrict__ crow,
                                        float t1, float t3, int code,
                                        unsigned long long* __restrict__ dst) {
  float e = dot256_np(rrow, crow);
  float dn = fa(fs(t1, fa(e, e)), t3);
  atomicMin(dst, ((unsigned long long)fkey(dn) << 32) | (unsigned)code);
}

// ---- z: np-exact chain per (m,d); LDS double-buffered w pipeline ----
__global__ __launch_bounds__(256) void k_z(const float* __restrict__ in,
                                           const float* __restrict__ w_in,
                                           float* __restrict__ residual) {
  const int m0 = blockIdx.x * 8;
  __shared__ float xs[8][FEAT];                    // 24192 B
  __shared__ __align__(16) float wsb[2][4][256];   //  8192 B
  for (int i = threadIdx.x; i < 8 * FEAT; i += 256)
    xs[i / FEAT][i % FEAT] = in[(size_t)m0 * FEAT + i];
  const int dg = threadIdx.x & 63;
  const int tg = threadIdx.x >> 6;
  const int srow = threadIdx.x >> 6;        // staging: row 0..3
  const int scol = (threadIdx.x & 63) * 4;  // staging: col
  {
    float4 v = *reinterpret_cast<const float4*>(&w_in[(size_t)srow * DIM + scol]);
    *reinterpret_cast<float4*>(&wsb[0][srow][scol]) = v;
  }
  __syncthreads();
  float4 a0 = {0.f, 0.f, 0.f, 0.f}, a1 = {0.f, 0.f, 0.f, 0.f};
  int cur = 0;
  for (int ch = 0; ch < 189; ++ch) {        // F = ch*4 + j, ascending; 252%4==0
    float4 nx = {0.f, 0.f, 0.f, 0.f};
    const bool has_next = (ch + 1 < 189);
    if (has_next)
      nx = *reinterpret_cast<const float4*>(
          &w_in[((size_t)(ch + 1) * 4 + srow) * DIM + scol]);
    const int c = (ch * 4) / 252;
    const int fb = ch * 4 - c * 252;
#pragma unroll
    for (int j = 0; j < 4; ++j) {
      float4 w4 = *reinterpret_cast<const float4*>(&wsb[cur][j][dg * 4]);
      float x0 = xs[tg * 2 + 0][(fb + j) * 3 + c];
      float x1 = xs[tg * 2 + 1][(fb + j) * 3 + c];
      a0.x = fa(a0.x, fm(x0, w4.x)); a0.y = fa(a0.y, fm(x0, w4.y));
      a0.z = fa(a0.z, fm(x0, w4.z)); a0.w = fa(a0.w, fm(x0, w4.w));
      a1.x = fa(a1.x, fm(x1, w4.x)); a1.y = fa(a1.y, fm(x1, w4.y));
      a1.z = fa(a1.z, fm(x1, w4.z)); a1.w = fa(a1.w, fm(x1, w4.w));
    }
    if (has_next)
      *reinterpret_cast<float4*>(&wsb[cur ^ 1][srow][scol]) = nx;
    __syncthreads();
    cur ^= 1;
  }
  *reinterpret_cast<float4*>(&residual[(size_t)(m0 + tg * 2 + 0) * DIM + dg * 4]) = a0;
  *reinterpret_cast<float4*>(&residual[(size_t)(m0 + tg * 2 + 1) * DIM + dg * 4]) = a1;
}

// ---- codebook row norms (np pairwise) ----
__global__ __launch_bounds__(256) void k_cbnorm(const float* __restrict__ cb,
                                                float* __restrict__ cbn) {
  int row = blockIdx.x * 256 + threadIdx.x;
  if (row >= NQ * NCODE) return;
  cbn[row] = pairwise256_sq(&cb[(size_t)row * DIM]);
}

// ---- codebook f32 -> bf16 bits ----
__global__ __launch_bounds__(256) void k_cb16(const float* __restrict__ cb,
                                              unsigned short* __restrict__ cb16) {
  size_t i = (size_t)blockIdx.x * 1024 + (size_t)threadIdx.x * 4;
  float4 v = *reinterpret_cast<const float4*>(&cb[i]);
  ushort4 o;
  o.x = bf16rne(v.x); o.y = bf16rne(v.y); o.z = bf16rne(v.z); o.w = bf16rne(v.w);
  *reinterpret_cast<ushort4*>(&cb16[i]) = o;
}

// ---- w_out transpose -> bf16 wT16[768][256] ----
__global__ __launch_bounds__(256) void k_wt(const float* __restrict__ w_out,
                                            unsigned short* __restrict__ wT16) {
  int n = blockIdx.x, k = threadIdx.x;
  float v = (n < FEAT) ? w_out[(size_t)k * FEAT + n] : 0.f;
  wT16[(size_t)n * DIM + k] = bf16rne(v);
}

// ---- np token norms + best64 reset (ONCE, before q=0) ----
__global__ __launch_bounds__(256) void k_t1(const float* __restrict__ residual,
                                            float* __restrict__ t1g,
                                            unsigned long long* __restrict__ best64) {
  int m = blockIdx.x * 256 + threadIdx.x;
  t1g[m] = pairwise256_sq(&residual[(size_t)m * DIM]);
  best64[m] = 0xFFFFFFFFFFFFFFFFull;
}

// ---- fused: 8-wave f-split MFMA screen + LDS repair + update + shuffle-t1 ----
__global__ __launch_bounds__(512) void k_screen(
    const unsigned short* __restrict__ cb16, const float* __restrict__ cb,
    const float* __restrict__ cbn, float* __restrict__ residual,
    float* __restrict__ t1g, unsigned long long* __restrict__ best64,
    float* __restrict__ allq, float* __restrict__ idxout, int q) {
  __shared__ __align__(16) unsigned short Bs[64][264];   // 33792 B
  __shared__ float cbn_s[NCODE];                         //  4096 B
  __shared__ unsigned list[LCAP];                        // 10240 B
  __shared__ unsigned list2[L2CAP];                      //  2048 B
  __shared__ unsigned fbs_u[64];
  __shared__ float t1_s[64], dlt_s[64];
  __shared__ unsigned lcnt, l2cnt;
  const int m0 = blockIdx.x * 64;
  const int tid = threadIdx.x, w = tid >> 6, lane = tid & 63;
  const int lrow = lane & 15, lk = lane >> 4;
  const int wg = w & 3, grp = w >> 2;          // token-quarter, f-half
  const unsigned short* cbq16 = cb16 + (size_t)q * NCODE * DIM;
  const float* cbqf = cb + (size_t)q * NCODE * DIM;

  for (int i = tid; i < NCODE; i += 512) cbn_s[i] = cbn[q * NCODE + i];
  if (tid < 64) {
    float t1 = t1g[m0 + tid];
    t1_s[tid] = t1;
    dlt_s[tid] = fmaxf(DSCALE * sqrtf(fmaxf(t1, 0.f)), 1e-5f);
    fbs_u[tid] = 0xFFFFFFFFu;
  }
  if (tid == 0) { lcnt = 0; l2cnt = 0; }

  // A fragments: token = m0 + wg*16 + lrow (f-half waves duplicate A loads)
  short8 afr[8];
  {
    const float* rrow = &residual[(size_t)(m0 + wg * 16 + lrow) * DIM];
#pragma unroll
    for (int s = 0; s < 8; ++s) {
      float4 x0 = *reinterpret_cast<const float4*>(&rrow[s * 32 + lk * 8]);
      float4 x1 = *reinterpret_cast<const float4*>(&rrow[s * 32 + lk * 8 + 4]);
      short8 t;
      t[0] = (short)bf16rne(x0.x); t[1] = (short)bf16rne(x0.y);
      t[2] = (short)bf16rne(x0.z); t[3] = (short)bf16rne(x0.w);
      t[4] = (short)bf16rne(x1.x); t[5] = (short)bf16rne(x1.y);
      t[6] = (short)bf16rne(x1.z); t[7] = (short)bf16rne(x1.w);
      afr[s] = t;
    }
  }
  __syncthreads();

  const int tokbase = wg * 16 + lk * 4;
  float dl[4];
#pragma unroll
  for (int r = 0; r < 4; ++r) dl[r] = dlt_s[tokbase + r];
  float runmin[4] = {FLT_MAX, FLT_MAX, FLT_MAX, FLT_MAX};
  int runcode[4] = {0, 0, 0, 0};

#define PUSH(PD, PC, R)                                                          \
  {                                                                              \
    unsigned idx_ = atomicAdd(&lcnt, 1u);                                        \
    if (idx_ < LCAP)                                                             \
      list[idx_] = (fkey(PD) & 0xFFFF0000u) |                                    \
                   ((unsigned)(tokbase + (R)) << 10) | (unsigned)(PC);           \
    else                                                                         \
      np_eval(&residual[(size_t)(m0 + tokbase + (R)) * DIM],                     \
              &cbqf[(size_t)(PC) * DIM], t1_s[tokbase + (R)], cbn_s[(PC)],       \
              (PC), &best64[m0 + tokbase + (R)]);                                \
  }

  for (int ct = 0; ct < 16; ++ct) {
    __syncthreads();
    {  // stage one 64-code tile: 2048 uint4 by 512 threads
#pragma unroll
      for (int k = 0; k < 4; ++k) {
        int f4 = tid + k * 512;
        int row = f4 >> 5, seg = f4 & 31;
        *reinterpret_cast<uint4*>(&Bs[row][seg * 8]) =
            *reinterpret_cast<const uint4*>(&cbq16[(size_t)(ct * 64 + row) * DIM + seg * 8]);
      }
    }
    __syncthreads();

    f32x4 acc[2];
    acc[0] = (f32x4){0.f, 0.f, 0.f, 0.f};
    acc[1] = (f32x4){0.f, 0.f, 0.f, 0.f};
#pragma unroll
    for (int s = 0; s < 8; ++s) {
#pragma unroll
      for (int f2 = 0; f2 < 2; ++f2) {
        const int f = grp * 2 + f2;
        short8 bfr = *reinterpret_cast<const short8*>(&Bs[f * 16 + lrow][s * 32 + lk * 8]);
        acc[f2] = __builtin_amdgcn_mfma_f32_16x16x32_bf16(afr[s], bfr, acc[f2], 0, 0, 0);
      }
    }

#pragma unroll
    for (int f2 = 0; f2 < 2; ++f2) {
      const int code = ct * 64 + (grp * 2 + f2) * 16 + lrow;
      const float t3 = cbn_s[code];
#pragma unroll
      for (int r = 0; r < 4; ++r) {
        const float d = t3 - 2.0f * acc[f2][r];
        if (d < runmin[r]) {
          if (runmin[r] <= d + dl[r]) PUSH(runmin[r], runcode[r], r);
          runmin[r] = d; runcode[r] = code;
        } else if (d <= runmin[r] + dl[r]) {
          PUSH(d, code, r);
        }
      }
    }
  }
#pragma unroll
  for (int r = 0; r < 4; ++r) PUSH(runmin[r], runcode[r], r);

  // per-token fast best: 16 lrow lanes within wave, cross-wave via LDS keys
  float fb[4] = {runmin[0], runmin[1], runmin[2], runmin[3]};
#pragma unroll
  for (int off = 8; off >= 1; off >>= 1)
#pragma unroll
    for (int r = 0; r < 4; ++r)
      fb[r] = fminf(fb[r], __shfl_xor(fb[r], off, 64));
  if (lrow == 0)
#pragma unroll
    for (int r = 0; r < 4; ++r)
      atomicMin(&fbs_u[tokbase + r], fkey(fb[r]));
  __syncthreads();

  // filter list -> survivors (df underestimated by key truncation: conservative)
  {
    unsigned n = lcnt; if (n > LCAP) n = LCAP;
    for (unsigned i = tid; i < n; i += 512) {
      unsigned e = list[i];
      unsigned tok = (e >> 10) & 63u;
      float df = funkey(e & 0xFFFF0000u);
      if (df <= funkey(fbs_u[tok]) + dlt_s[tok]) {
        unsigned j = atomicAdd(&l2cnt, 1u);
        if (j < L2CAP) list2[j] = e & 0xFFFFu;
        else np_eval(&residual[(size_t)(m0 + tok) * DIM],
                     &cbqf[(size_t)(e & 1023u) * DIM], t1_s[tok],
                     cbn_s[e & 1023u], (int)(e & 1023u), &best64[m0 + tok]);
      }
    }
  }
  __syncthreads();

  // cooperative np-exact repair: 4 lanes per candidate, 16/wave, 8 waves
  {
    unsigned n2 = l2cnt; if (n2 > L2CAP) n2 = L2CAP;
    const int j4 = lane & 3, g = lane >> 2;
    for (unsigned i0 = (unsigned)w * 16u; i0 < n2; i0 += 128u) {
      unsigned ci = i0 + (unsigned)g;
      bool act = ci < n2;
      unsigned ent = act ? list2[ci] : 0u;
      unsigned tok = (ent >> 10) & 63u, code = ent & 1023u;
      const float* rr = &residual[(size_t)(m0 + tok) * DIM];
      const float* cc2 = &cbqf[(size_t)code * DIM];
      float L = 0.f;
#pragma unroll 8
      for (int t = 0; t < 64; ++t)
        L = fa(L, fm(rr[4 * t + j4], cc2[4 * t + j4]));
      float tmp = fa(L, __shfl_xor(L, 2, 64));
      float e4 = fa(tmp, __shfl_xor(tmp, 1, 64));
      if (act && j4 == 0) {
        float dn = fa(fs(t1_s[tok], fa(e4, e4)), cbn_s[code]);
        atomicMin(&best64[m0 + tok],
                  ((unsigned long long)fkey(dn) << 32) | code);
      }
    }
  }
  __syncthreads();

  // update: residual step (np fs), allq, idx; t1 via shuffle tree (np pairwise order)
  for (int t = 0; t < 8; ++t) {
    const int tok = w * 8 + t;
    const size_t m = (size_t)m0 + tok;
    const int ci = (int)(best64[m] & 0xFFFFFFFFull);
    const float4 cv = *reinterpret_cast<const float4*>(&cbqf[(size_t)ci * DIM + lane * 4]);
    const size_t base = m * DIM + lane * 4;
    float4 r = *reinterpret_cast<const float4*>(&residual[base]);
    r.x = fs(r.x, cv.x); r.y = fs(r.y, cv.y); r.z = fs(r.z, cv.z); r.w = fs(r.w, cv.w);
    *reinterpret_cast<float4*>(&residual[base]) = r;
    *reinterpret_cast<float4*>(&allq[((size_t)q * M_TOK + m) * DIM + lane * 4]) = cv;
    // lane L holds elements 4L..4L+3; np pw128 per 32-lane half, halves joined.
    float qs[4] = {fm(r.x, r.x), fm(r.y, r.y), fm(r.z, r.z), fm(r.w, r.w)};
    float W[4];
#pragma unroll
    for (int l = 0; l < 4; ++l) {
      float v = qs[l];
      float s1 = __shfl_down(v, 8, 64);
      float s2 = __shfl_down(v, 16, 64);
      float s3 = __shfl_down(v, 24, 64);
      float V = fa(fa(fa(v, s1), s2), s3);       // lanes 0-7 / 32-39 valid
      float A = fa(V, __shfl_down(V, 1, 64));
      float B = fa(A, __shfl_down(A, 2, 64));
      W[l] = fa(B, __shfl_down(B, 4, 64));       // lanes 0 / 32 valid
    }
    float hsum = fa(fa(W[0], W[2]), fa(W[1], W[3]));
    float up = __shfl(hsum, 32, 64);
    if (lane == 0) {
      t1g[m] = fa(hsum, up);
      best64[m] = 0xFFFFFFFFFFFFFFFFull;
      idxout[m * NQ + q] = (float)ci;
    }
  }
#undef PUSH
}

// ---- quantized = relu( (sum_q allq) @ w_out ), MFMA bf16; one block = 64 tokens ----
__global__ __launch_bounds__(256) void k_gemm_out(const float* __restrict__ allq,
                                                  const unsigned short* __restrict__ wT16,
                                                  float* __restrict__ C) {
  __shared__ __align__(16) unsigned short As[64][264];
  __shared__ __align__(16) unsigned short Bs[64][264];
  const int m0 = blockIdx.x * 64;
  const int tid = threadIdx.x, w = tid >> 6, lane = tid & 63;
  const int lrow = lane & 15, lk = lane >> 4;

#pragma unroll
  for (int k4 = 0; k4 < 16; ++k4) {
    int f4 = tid + k4 * 256;
    int tok = f4 >> 6, dseg = f4 & 63;
    float4 v = {0.f, 0.f, 0.f, 0.f};
#pragma unroll
    for (int qq = 0; qq < NQ; ++qq) {
      float4 t = *reinterpret_cast<const float4*>(
          &allq[((size_t)qq * M_TOK + m0 + tok) * DIM + dseg * 4]);
      v.x = fa(v.x, t.x); v.y = fa(v.y, t.y); v.z = fa(v.z, t.z); v.w = fa(v.w, t.w);
    }
    ushort4 o;
    o.x = bf16rne(v.x); o.y = bf16rne(v.y); o.z = bf16rne(v.z); o.w = bf16rne(v.w);
    *reinterpret_cast<ushort4*>(&As[tok][dseg * 4]) = o;
  }
  __syncthreads();

  short8 afr[8];
#pragma unroll
  for (int s = 0; s < 8; ++s)
    afr[s] = *reinterpret_cast<const short8*>(&As[w * 16 + lrow][s * 32 + lk * 8]);

  for (int nt = 0; nt < 12; ++nt) {
    const int n0 = nt * 64;
    __syncthreads();
    {
      int r = tid >> 2, seg = tid & 3;
      const uint4* src = reinterpret_cast<const uint4*>(&wT16[(size_t)(n0 + r) * DIM + seg * 64]);
      uint4* dst = reinterpret_cast<uint4*>(&Bs[r][seg * 64]);
#pragma unroll
      for (int u = 0; u < 8; ++u) dst[u] = src[u];
    }
    __syncthreads();

    f32x4 acc[4];
#pragma unroll
    for (int f = 0; f < 4; ++f) acc[f] = (f32x4){0.f, 0.f, 0.f, 0.f};
#pragma unroll
    for (int s = 0; s < 8; ++s) {
#pragma unroll
      for (int f = 0; f < 4; ++f) {
        short8 bfr = *reinterpret_cast<const short8*>(&Bs[f * 16 + lrow][s * 32 + lk * 8]);
        acc[f] = __builtin_amdgcn_mfma_f32_16x16x32_bf16(afr[s], bfr, acc[f], 0, 0, 0);
      }
    }

#pragma unroll
    for (int f = 0; f < 4; ++f) {
      const int col = n0 + f * 16 + lrow;
      if (col < FEAT) {
#pragma unroll
        for (int r = 0; r < 4; ++r)
          C[(size_t)(m0 + w * 16 + lk * 4 + r) * FEAT + col] = fmaxf(acc[f][r], 0.f);
      }
    }
  }
}

extern "C" void kernel_launch(void* const* d_in, const int* in_sizes, int n_in,
                              void* d_out, int out_size, void* d_ws, size_t ws_size,
                              hipStream_t stream) {
  int i_inputs = 0, i_cb = 1, iA = 2, iB = 3;
  {
    int a = -1, b = -1, ii = -1, ic = -1;
    for (int i = 0; i < n_in; ++i) {
      if (in_sizes[i] == M_TOK * FEAT) ii = i;
      else if (in_sizes[i] == NQ * NCODE * DIM) ic = i;
      else if (in_sizes[i] == FEAT * DIM) { if (a < 0) a = i; else b = i; }
    }
    if (ii >= 0 && ic >= 0 && a >= 0 && b >= 0) { i_inputs = ii; i_cb = ic; iA = a; iB = b; }
  }
  const float* inputs = (const float*)d_in[i_inputs];
  const float* cb     = (const float*)d_in[i_cb];
  const float* w_in   = (const float*)d_in[iA];
  const float* w_out  = (const float*)d_in[iB];

  float* out       = (float*)d_out;
  float* quantized = out;                                 // 16384*756
  float* allq      = out + (size_t)M_TOK * FEAT;          // 8*16384*256
  float* idxout    = allq + (size_t)NQ * M_TOK * DIM;     // 16384*8

  // residual (16.8MB) lives in the quantized region (dead before k_gemm_out).
  float* residual = quantized;

  // Small scratch in d_ws (~4.8 MB). k_gemm_out reads only allq (output) + wT16 (ws).
  char* ws = (char*)d_ws;
  unsigned short*     cb16   = (unsigned short*)(ws);                 // 4,194,304 B
  unsigned short*     wT16   = (unsigned short*)(ws + 4194304);       //   393,216 B
  float*              cbn    = (float*)(ws + 4587520);                //    32,768 B
  float*              t1g    = (float*)(ws + 4620288);                //    65,536 B
  unsigned long long* best64 = (unsigned long long*)(ws + 4685824);   //   131,072 B

  k_z<<<M_TOK / 8, 256, 0, stream>>>(inputs, w_in, residual);
  k_cbnorm<<<NQ * NCODE / 256, 256, 0, stream>>>(cb, cbn);
  k_cb16<<<NQ * NCODE * DIM / 1024, 256, 0, stream>>>(cb, cb16);
  k_wt<<<768, 256, 0, stream>>>(w_out, wT16);
  k_t1<<<M_TOK / 256, 256, 0, stream>>>(residual, t1g, best64);
  for (int q = 0; q < NQ; ++q)
    k_screen<<<M_TOK / 64, 512, 0, stream>>>(cb16, cb, cbn, residual, t1g, best64,
                                             allq, idxout, q);
  k_gemm_out<<<M_TOK / 64, 256, 0, stream>>>(allq, wT16, quantized);
}